// Round 6
// baseline (534.353 us; speedup 1.0000x reference)
//
#include <hip/hip_runtime.h>
#include <hip/hip_bf16.h>

#define LLEN 384
#define CDIM 256
#define NH 8
#define HD 32
#define DIN 128
#define LN_EPS 1e-5f
#define SCL 0.17677669529663687f   // 1/sqrt(32)

// XOR-swizzled LDS addressing (cs = column offset in shorts, multiple of 4).
#define EIDX(row, cs) (((row) << 8) + (((((cs) >> 3) ^ ((row) & 7)) << 3) | ((cs) & 4)))
#define XIDX(row, cs) (((row) << 7) + (((((cs) >> 3) ^ ((row) & 7)) << 3) | ((cs) & 4)))

typedef __attribute__((ext_vector_type(8))) short bh8;
typedef __attribute__((ext_vector_type(4))) float f32x4;
typedef __attribute__((ext_vector_type(4))) unsigned int u32x4;

__device__ __forceinline__ unsigned short f2bf(float f){
  unsigned int u = __float_as_uint(f);
  u += 0x7fffu + ((u >> 16) & 1u);
  return (unsigned short)(u >> 16);
}

__device__ __forceinline__ unsigned int pkbf(float a, float b){
#if defined(__gfx950__) && __has_builtin(__builtin_amdgcn_cvt_pk_bf16_f32)
  typedef __attribute__((ext_vector_type(2))) __bf16 vbf2;
  vbf2 v = __builtin_amdgcn_cvt_pk_bf16_f32(a, b);
  union { vbf2 v; unsigned int u; } cv; cv.v = v; return cv.u;
#else
  return (unsigned int)f2bf(a) | ((unsigned int)f2bf(b) << 16);
#endif
}

// ---------------------------------------------------------------------------
// Pack weights (fp32 row-major [K][N]) into bf16 MFMA fragment order.
// ---------------------------------------------------------------------------
__global__ __launch_bounds__(256) void pack_w(
    const float* __restrict__ Wpre, const float* __restrict__ Weq,
    const float* __restrict__ Wek,  const float* __restrict__ Wq,
    const float* __restrict__ Wk,   const float* __restrict__ Wv,
    unsigned short* __restrict__ Pp, unsigned short* __restrict__ Pq,
    unsigned short* __restrict__ Pk, unsigned short* __restrict__ PWq,
    unsigned short* __restrict__ PWk, unsigned short* __restrict__ PWv)
{
  int tid = blockIdx.x * 256 + threadIdx.x;   // 176 blocks * 256 = 45056
  const float* W; unsigned short* P; int base;
  if      (tid <  4096){ W = Wpre; P = Pp;  base = tid;         }
  else if (tid < 12288){ W = Weq;  P = Pq;  base = tid -  4096; }
  else if (tid < 20480){ W = Wek;  P = Pk;  base = tid - 12288; }
  else if (tid < 28672){ W = Wq;   P = PWq; base = tid - 20480; }
  else if (tid < 36864){ W = Wk;   P = PWk; base = tid - 28672; }
  else                 { W = Wv;   P = PWv; base = tid - 36864; }
  int l   = base & 63;
  int c   = (base >> 6) & 15;
  int kc  = base >> 10;
  int krow = kc*32 + (l >> 4)*8;
  int col  = c*16 + (l & 15);
  unsigned int wds[4];
  #pragma unroll
  for (int p = 0; p < 4; p++){
    unsigned short lo = f2bf(W[(size_t)(krow + 2*p    )*CDIM + col]);
    unsigned short hi = f2bf(W[(size_t)(krow + 2*p + 1)*CDIM + col]);
    wds[p] = (unsigned int)lo | ((unsigned int)hi << 16);
  }
  uint4 v; v.x = wds[0]; v.y = wds[1]; v.z = wds[2]; v.w = wds[3];
  *(uint4*)(P + (size_t)base*8) = v;
}

// ---------------------------------------------------------------------------
// qkv: 18 blocks (jb 0..5 x m 0..2).
// ---------------------------------------------------------------------------
__global__ __launch_bounds__(256) void qkv_mfma(
    const float* __restrict__ x3d,
    const float* __restrict__ bq, const float* __restrict__ bk, const float* __restrict__ bv,
    const unsigned short* __restrict__ PWq, const unsigned short* __restrict__ PWk,
    const unsigned short* __restrict__ PWv,
    float* __restrict__ Vm, unsigned short* __restrict__ QmH,
    float* __restrict__ QmT, unsigned short* __restrict__ PKt)
{
  __shared__ __align__(16) unsigned short Xb[64*264];
  const int bx = blockIdx.x;
  const int jb = bx / 3, m = bx % 3;
  const int t  = threadIdx.x;
  const int w  = t >> 6, l = t & 63, q4 = l >> 4, lm = l & 15;
  const int wbase = w << 6;

  const float* src = x3d + (size_t)jb*64*CDIM;
  #pragma unroll
  for (int it = 0; it < 16; it++){
    int idx = it*256 + t;
    int r = idx >> 6, k4 = (idx & 63) << 2;
    f32x4 v = *(const f32x4*)(src + (size_t)r*CDIM + k4);
    uint2 pk; pk.x = pkbf(v[0], v[1]); pk.y = pkbf(v[2], v[3]);
    *(uint2*)(&Xb[r*264 + k4]) = pk;
  }
  __syncthreads();

  const unsigned short* P = (m == 0) ? PWq : (m == 1) ? PWk : PWv;
  const float* bias       = (m == 0) ? bq  : (m == 1) ? bk  : bv;
  f32x4 acc[4][4];
  #pragma unroll
  for (int a = 0; a < 4; a++)
    #pragma unroll
    for (int b = 0; b < 4; b++){ f32x4 z = {0.f,0.f,0.f,0.f}; acc[a][b] = z; }
  #pragma unroll
  for (int kc = 0; kc < 8; kc++){
    bh8 af[4];
    #pragma unroll
    for (int rt = 0; rt < 4; rt++)
      af[rt] = *(const bh8*)(&Xb[(rt*16 + lm)*264 + kc*32 + q4*8]);
    #pragma unroll
    for (int ct = 0; ct < 4; ct++){
      bh8 bf = *(const bh8*)(P + ((size_t)(kc*16 + (w*4 + ct))*64 + l)*8);
      #pragma unroll
      for (int rt = 0; rt < 4; rt++)
        acc[rt][ct] = __builtin_amdgcn_mfma_f32_16x16x32_bf16(af[rt], bf, acc[rt][ct], 0, 0, 0);
    }
  }
  #pragma unroll
  for (int ct = 0; ct < 4; ct++){
    int c = wbase + ct*16 + lm;
    float bb = bias[c];
    #pragma unroll
    for (int rt = 0; rt < 4; rt++)
      #pragma unroll
      for (int rg = 0; rg < 4; rg++){
        int row = jb*64 + rt*16 + q4*4 + rg;
        float v = acc[rt][ct][rg] + bb;
        if (m == 0){
          QmH[(size_t)row*CDIM + c] = f2bf(v);
          QmT[(size_t)c*LLEN + row] = v;
        } else if (m == 1){
          int kc2 = c >> 5;            // head
          int jj2 = c & 7;
          int l2  = ((c >> 3) & 3)*16 + (row & 15);
          PKt[(((size_t)kc2*24 + (row >> 4))*64 + l2)*8 + jj2] = f2bf(v);
        } else {
          Vm[(size_t)row*CDIM + c] = v;
        }
      }
  }
}

// ---------------------------------------------------------------------------
// Main kernel: 768 blocks = i(384) x jh(2); each loops 3 j-tiles of 64.
// 3 blocks/CU, all resident. x2d staging register-prefetched one tile ahead.
// ---------------------------------------------------------------------------
__global__ __launch_bounds__(256, 3) void x3d_tiles(
  const float* __restrict__ x2d,
  const float* __restrict__ bpre, const float* __restrict__ ln_g, const float* __restrict__ ln_b,
  const float* __restrict__ beq,  const float* __restrict__ bek,
  const float* __restrict__ QmT,  const unsigned short* __restrict__ QmH,
  const unsigned short* __restrict__ PKt,
  const unsigned short* __restrict__ Pp, const unsigned short* __restrict__ Pq,
  const unsigned short* __restrict__ Pk,
  float* __restrict__ Sg, float* __restrict__ x2part)
{
  __shared__ __align__(16) unsigned short XS[64*128];      // 16384 B (X, swizzled)
  __shared__ __align__(16) unsigned short ES[64*256];      // 32768 B (E, swizzled)
  __shared__ float rowstat[4][64][2];                      //  2048 B
  __shared__ float muS[64], istdS[64];                     //   512 B
  __shared__ __align__(16) float scoresS[NH*64];           //  2048 B
  // total 53760 B -> exactly 3 blocks/CU

  const int bx = blockIdx.x;
  const int i = bx >> 1, jh = bx & 1;
  const int t = threadIdx.x;
  const int w = t >> 6, l = t & 63, q4 = l >> 4, lm = l & 15;
  const int wbase = w << 6;
  const bool b4 = l & 16, b5 = l & 32;
  const int pr  = (t >> 5);        // staging row sub-index
  const int pk4 = (t & 31) * 4;    // staging col (floats)

  float x2p[4] = {0.f, 0.f, 0.f, 0.f};

  // initial prefetch of tile 0
  u32x4 pf[8];
  {
    const float* src = x2d + ((size_t)i*LLEN + jh*192)*DIN;
    #pragma unroll
    for (int it = 0; it < 8; it++)
      pf[it] = __builtin_nontemporal_load((const u32x4*)(src + (size_t)(it*8 + pr)*DIN + pk4));
  }

  for (int tt = 0; tt < 3; tt++){
    const int j0 = jh*192 + tt*64;
    const int jt = jh*3 + tt;

    // ---- write X tile from prefetch regs ----
    #pragma unroll
    for (int it = 0; it < 8; it++){
      uint2 pkv;
      pkv.x = pkbf(__uint_as_float(pf[it].x), __uint_as_float(pf[it].y));
      pkv.y = pkbf(__uint_as_float(pf[it].z), __uint_as_float(pf[it].w));
      *(uint2*)(&XS[XIDX(it*8 + pr, pk4)]) = pkv;
    }
    // ---- issue prefetch for next tile (in flight across this tile's math) ----
    if (tt < 2){
      const float* src = x2d + ((size_t)i*LLEN + j0 + 64)*DIN;
      #pragma unroll
      for (int it = 0; it < 8; it++)
        pf[it] = __builtin_nontemporal_load((const u32x4*)(src + (size_t)(it*8 + pr)*DIN + pk4));
    }

    // ---- term1 via MFMA: scoresS[h][j] = q_i(h).k_j(h) (wave-local rows) ----
    #pragma unroll
    for (int hh = 0; hh < 2; hh++){
      int h = 2*w + hh;
      bh8 aq = *(const bh8*)(QmH + (size_t)i*CDIM + h*HD + q4*8);
      #pragma unroll
      for (int ct = 0; ct < 4; ct++){
        bh8 bf = *(const bh8*)(PKt + (((size_t)h*24 + (jt*4 + ct))*64 + l)*8);
        f32x4 z = {0.f,0.f,0.f,0.f};
        f32x4 a1 = __builtin_amdgcn_mfma_f32_16x16x32_bf16(aq, bf, z, 0, 0, 0);
        if (q4 == 0) scoresS[h*64 + ct*16 + lm] = a1[0];
      }
    }
    __syncthreads();   // X ready (and prior tile's E reads all done)

    // ---- GEMM1 (swapped): acc[mt][nt], c = wbase+mt*16+q4*4+rg, j = nt*16+lm
    f32x4 acc[4][4];
    #pragma unroll
    for (int a = 0; a < 4; a++)
      #pragma unroll
      for (int b = 0; b < 4; b++){ f32x4 z = {0.f,0.f,0.f,0.f}; acc[a][b] = z; }
    #pragma unroll
    for (int kc = 0; kc < 4; kc++){
      bh8 xf[4];
      #pragma unroll
      for (int nt = 0; nt < 4; nt++)
        xf[nt] = *(const bh8*)(&XS[XIDX(nt*16 + lm, kc*32 + q4*8)]);
      #pragma unroll
      for (int mt = 0; mt < 4; mt++){
        bh8 wf = *(const bh8*)(Pp + ((size_t)(kc*16 + (w*4 + mt))*64 + l)*8);
        #pragma unroll
        for (int nt = 0; nt < 4; nt++)
          acc[mt][nt] = __builtin_amdgcn_mfma_f32_16x16x32_bf16(wf, xf[nt], acc[mt][nt], 0, 0, 0);
      }
    }

    // ---- + bpre, LN stats per j ----
    {
      float vs[4] = {0,0,0,0}, vq[4] = {0,0,0,0};
      #pragma unroll
      for (int mt = 0; mt < 4; mt++){
        int cb = wbase + mt*16 + q4*4;
        f32x4 bp = *(const f32x4*)(bpre + cb);
        #pragma unroll
        for (int nt = 0; nt < 4; nt++)
          #pragma unroll
          for (int rg = 0; rg < 4; rg++){
            float x = acc[mt][nt][rg] + bp[rg];
            acc[mt][nt][rg] = x;
            vs[nt] += x; vq[nt] += x*x;
          }
      }
      float r0 = (b4 ? vs[1] : vs[0]) + __shfl_xor(b4 ? vs[0] : vs[1], 16, 64);
      float r1 = (b4 ? vs[3] : vs[2]) + __shfl_xor(b4 ? vs[2] : vs[3], 16, 64);
      float ssum = (b5 ? r1 : r0) + __shfl_xor(b5 ? r0 : r1, 32, 64);
      float u0 = (b4 ? vq[1] : vq[0]) + __shfl_xor(b4 ? vq[0] : vq[1], 16, 64);
      float u1 = (b4 ? vq[3] : vq[2]) + __shfl_xor(b4 ? vq[2] : vq[3], 16, 64);
      float ssq = (b5 ? u1 : u0) + __shfl_xor(b5 ? u0 : u1, 32, 64);
      int ntl = (b5 ? 2 : 0) + (b4 ? 1 : 0);
      int jl = ntl*16 + lm;
      rowstat[w][jl][0] = ssum;
      rowstat[w][jl][1] = ssq;
    }
    __syncthreads();
    if (t < 64){
      float s  = rowstat[0][t][0] + rowstat[1][t][0] + rowstat[2][t][0] + rowstat[3][t][0];
      float s2 = rowstat[0][t][1] + rowstat[1][t][1] + rowstat[2][t][1] + rowstat[3][t][1];
      float mu = s * (1.f/256.f);
      float var = s2 * (1.f/256.f) - mu*mu;
      muS[t] = mu;
      istdS[t] = rsqrtf(var + LN_EPS);
    }
    __syncthreads();

    // ---- LN + ReLU -> bf16 E tile ----
    {
      float muL[4], isL[4];
      #pragma unroll
      for (int nt = 0; nt < 4; nt++){
        muL[nt] = muS[nt*16 + lm];
        isL[nt] = istdS[nt*16 + lm];
      }
      #pragma unroll
      for (int mt = 0; mt < 4; mt++){
        int cb = wbase + mt*16 + q4*4;
        f32x4 g4 = *(const f32x4*)(ln_g + cb);
        f32x4 bb4 = *(const f32x4*)(ln_b + cb);
        #pragma unroll
        for (int nt = 0; nt < 4; nt++){
          float e0 = fmaxf((acc[mt][nt][0] - muL[nt])*isL[nt]*g4[0] + bb4[0], 0.f);
          float e1 = fmaxf((acc[mt][nt][1] - muL[nt])*isL[nt]*g4[1] + bb4[1], 0.f);
          float e2 = fmaxf((acc[mt][nt][2] - muL[nt])*isL[nt]*g4[2] + bb4[2], 0.f);
          float e3 = fmaxf((acc[mt][nt][3] - muL[nt])*isL[nt]*g4[3] + bb4[3], 0.f);
          uint2 pkv; pkv.x = pkbf(e0, e1); pkv.y = pkbf(e2, e3);
          *(uint2*)(&ES[EIDX(nt*16 + lm, cb)]) = pkv;
        }
      }
    }
    __syncthreads();

    // ---- GEMM2 (swapped): acc = EFK^T ----
    #pragma unroll
    for (int a = 0; a < 4; a++)
      #pragma unroll
      for (int b = 0; b < 4; b++){ f32x4 z = {0.f,0.f,0.f,0.f}; acc[a][b] = z; }
    #pragma unroll
    for (int kc = 0; kc < 8; kc++){
      bh8 xf[4];
      #pragma unroll
      for (int nt = 0; nt < 4; nt++)
        xf[nt] = *(const bh8*)(&ES[EIDX(nt*16 + lm, kc*32 + q4*8)]);
      #pragma unroll
      for (int mt = 0; mt < 4; mt++){
        bh8 wf = *(const bh8*)(Pk + ((size_t)(kc*16 + (w*4 + mt))*64 + l)*8);
        #pragma unroll
        for (int nt = 0; nt < 4; nt++)
          acc[mt][nt] = __builtin_amdgcn_mfma_f32_16x16x32_bf16(wf, xf[nt], acc[mt][nt], 0, 0, 0);
      }
    }

    // ---- scores: coalesced QmT loads + 2-shuffle head reduce ----
    {
      f32x4 bk4[4];
      #pragma unroll
      for (int mt = 0; mt < 4; mt++)
        bk4[mt] = *(const f32x4*)(bek + wbase + mt*16 + q4*4);
      #pragma unroll
      for (int nt = 0; nt < 4; nt++){
        int j = nt*16 + lm;
        float qr[4][4];
        #pragma unroll
        for (int mt = 0; mt < 4; mt++){
          int cb = wbase + mt*16 + q4*4;
          #pragma unroll
          for (int rg = 0; rg < 4; rg++)
            qr[mt][rg] = QmT[(size_t)(cb + rg)*LLEN + j0 + j];
        }
        float v0 = 0.f, v1 = 0.f;
        #pragma unroll
        for (int mt = 0; mt < 4; mt++){
          float p = (acc[mt][nt][0] + bk4[mt][0]) * qr[mt][0]
                  + (acc[mt][nt][1] + bk4[mt][1]) * qr[mt][1]
                  + (acc[mt][nt][2] + bk4[mt][2]) * qr[mt][2]
                  + (acc[mt][nt][3] + bk4[mt][3]) * qr[mt][3];
          if (mt < 2) v0 += p; else v1 += p;
        }
        float r = (b4 ? v1 : v0) + __shfl_xor(b4 ? v0 : v1, 16, 64);
        float s = r + __shfl_xor(r, 32, 64);
        int h = 2*w + (b4 ? 1 : 0);
        float sc = (s + scoresS[h*64 + j]) * SCL;
        if (!b5){
          scoresS[h*64 + j] = sc;
          Sg[((size_t)i*NH + h)*LLEN + j0 + j] = sc;
        }
      }
    }

    // ---- GEMM3 (unswapped): acc = EFQ, j on rows, c on lanes ----
    #pragma unroll
    for (int a = 0; a < 4; a++)
      #pragma unroll
      for (int b = 0; b < 4; b++){ f32x4 z = {0.f,0.f,0.f,0.f}; acc[a][b] = z; }
    #pragma unroll
    for (int kc = 0; kc < 8; kc++){
      bh8 af[4];
      #pragma unroll
      for (int rt = 0; rt < 4; rt++)
        af[rt] = *(const bh8*)(&ES[EIDX(rt*16 + lm, kc*32 + q4*8)]);
      #pragma unroll
      for (int ct = 0; ct < 4; ct++){
        bh8 bf = *(const bh8*)(Pq + ((size_t)(kc*16 + (w*4 + ct))*64 + l)*8);
        #pragma unroll
        for (int rt = 0; rt < 4; rt++)
          acc[rt][ct] = __builtin_amdgcn_mfma_f32_16x16x32_bf16(af[rt], bf, acc[rt][ct], 0, 0, 0);
      }
    }

    // ---- x2 partials accumulate in regs across tiles ----
    {
      float bq4[4];
      #pragma unroll
      for (int ct = 0; ct < 4; ct++) bq4[ct] = beq[wbase + ct*16 + lm];
      #pragma unroll
      for (int rt = 0; rt < 4; rt++){
        f32x4 s0 = *(const f32x4*)(&scoresS[(2*w    )*64 + rt*16 + q4*4]);
        f32x4 s1 = *(const f32x4*)(&scoresS[(2*w + 1)*64 + rt*16 + q4*4]);
        #pragma unroll
        for (int ct = 0; ct < 4; ct++){
          const f32x4& sv = (ct < 2) ? s0 : s1;
          #pragma unroll
          for (int rg = 0; rg < 4; rg++)
            x2p[ct] = fmaf(sv[rg], acc[rt][ct][rg] + bq4[ct], x2p[ct]);
        }
      }
    }
  } // tile loop

  // ---- final x2 reduce (once per block) ----
  {
    float r0 = (b4 ? x2p[1] : x2p[0]) + __shfl_xor(b4 ? x2p[0] : x2p[1], 16, 64);
    float r1 = (b4 ? x2p[3] : x2p[2]) + __shfl_xor(b4 ? x2p[2] : x2p[3], 16, 64);
    float q  = (b5 ? r1 : r0) + __shfl_xor(b5 ? r0 : r1, 32, 64);
    int ctq = (b4 ? 1 : 0) | (b5 ? 2 : 0);
    x2part[((size_t)jh*LLEN + i)*CDIM + wbase + ctq*16 + lm] = q;
  }
}

// ---------------------------------------------------------------------------
// finish: softmax + x1 + x2 + out-proj. 384 blocks.
// ---------------------------------------------------------------------------
__global__ __launch_bounds__(256) void finish(
    const float* __restrict__ Sg, const float* __restrict__ x2part,
    const float* __restrict__ Vm, const float* __restrict__ Wo,
    const float* __restrict__ bo, float* __restrict__ out)
{
  __shared__ float scoresS[NH*LLEN];   // 12 KB
  __shared__ float xoutS[CDIM];
  const int i = blockIdx.x;
  const int t = threadIdx.x;

  #pragma unroll
  for (int it = 0; it < 3; it++)
    ((float4*)scoresS)[it*256 + t] = ((const float4*)(Sg + (size_t)i*NH*LLEN))[it*256 + t];
  __syncthreads();

  const int h = t >> 5;
  const int g32 = t & 31;
  float sv[12];
  float mx = -3.0e38f;
  #pragma unroll
  for (int it = 0; it < 12; it++){
    float s = scoresS[h*LLEN + it*32 + g32];
    sv[it] = s;
    mx = fmaxf(mx, s);
  }
  #pragma unroll
  for (int mk = 1; mk < 32; mk <<= 1) mx = fmaxf(mx, __shfl_xor(mx, mk, 64));
  float den = 0.f;
  #pragma unroll
  for (int it = 0; it < 12; it++){ float e = __expf(sv[it] - mx); sv[it] = e; den += e; }
  #pragma unroll
  for (int mk = 1; mk < 32; mk <<= 1) den += __shfl_xor(den, mk, 64);
  float rden = 1.f / den;
  #pragma unroll
  for (int it = 0; it < 12; it++) scoresS[h*LLEN + it*32 + g32] = sv[it]*rden;
  __syncthreads();

  float a0 = 0.f, a1 = 0.f, a2 = 0.f, a3 = 0.f;
  {
    const float* vp = Vm + t;
    const float* sp = scoresS + h*LLEN;
    #pragma unroll 4
    for (int j = 0; j < LLEN; j += 4){
      a0 = fmaf(sp[j+0], vp[(size_t)(j+0)*CDIM], a0);
      a1 = fmaf(sp[j+1], vp[(size_t)(j+1)*CDIM], a1);
      a2 = fmaf(sp[j+2], vp[(size_t)(j+2)*CDIM], a2);
      a3 = fmaf(sp[j+3], vp[(size_t)(j+3)*CDIM], a3);
    }
  }
  float x2v = x2part[(size_t)i*CDIM + t] + x2part[((size_t)LLEN + i)*CDIM + t];
  xoutS[t] = (a0 + a1) + (a2 + a3) + x2v;
  __syncthreads();

  float b0a = bo[t], b1a = 0.f, b2a = 0.f, b3a = 0.f;
  #pragma unroll 4
  for (int c = 0; c < CDIM; c += 4){
    b0a = fmaf(xoutS[c+0], Wo[(size_t)(c+0)*CDIM + t], b0a);
    b1a = fmaf(xoutS[c+1], Wo[(size_t)(c+1)*CDIM + t], b1a);
    b2a = fmaf(xoutS[c+2], Wo[(size_t)(c+2)*CDIM + t], b2a);
    b3a = fmaf(xoutS[c+3], Wo[(size_t)(c+3)*CDIM + t], b3a);
  }
  out[(size_t)i*CDIM + t] = (b0a + b1a) + (b2a + b3a);
}

// ---------------------------------------------------------------------------
extern "C" void kernel_launch(void* const* d_in, const int* in_sizes, int n_in,
                              void* d_out, int out_size, void* d_ws, size_t ws_size,
                              hipStream_t stream)
{
  const float* x2d  = (const float*)d_in[0];
  const float* x3d  = (const float*)d_in[1];
  const float* Wq   = (const float*)d_in[2];
  const float* bq   = (const float*)d_in[3];
  const float* Wk   = (const float*)d_in[4];
  const float* bk   = (const float*)d_in[5];
  const float* Wv   = (const float*)d_in[6];
  const float* bv   = (const float*)d_in[7];
  const float* Wpre = (const float*)d_in[8];
  const float* bpre = (const float*)d_in[9];
  const float* ln_g = (const float*)d_in[10];
  const float* ln_b = (const float*)d_in[11];
  const float* Weq  = (const float*)d_in[12];
  const float* beq  = (const float*)d_in[13];
  const float* Wek  = (const float*)d_in[14];
  const float* bek  = (const float*)d_in[15];
  const float* Wo   = (const float*)d_in[16];
  const float* bo   = (const float*)d_in[17];
  float* out = (float*)d_out;

  float* Vm  = (float*)d_ws;                                 // 384*256 f32
  float* QmT = Vm + LLEN*CDIM;                               // 256*384 f32
  unsigned short* QmH = (unsigned short*)(QmT + CDIM*LLEN);  // 384*256 bf16
  unsigned short* PKt = QmH + LLEN*CDIM;                     // 8*24*64*8 bf16
  unsigned short* Pp  = PKt + LLEN*CDIM;                     // 128*256
  unsigned short* Pq  = Pp  + DIN*CDIM;                      // 256*256
  unsigned short* Pk  = Pq  + CDIM*CDIM;
  unsigned short* PWq = Pk  + CDIM*CDIM;
  unsigned short* PWk = PWq + CDIM*CDIM;
  unsigned short* PWv = PWk + CDIM*CDIM;
  float* Sg     = (float*)(PWv + CDIM*CDIM);                 // 384*8*384 f32
  float* x2part = Sg + (size_t)LLEN*NH*LLEN;                 // 2*384*256 f32

  pack_w<<<dim3(176), dim3(256), 0, stream>>>(Wpre, Weq, Wek, Wq, Wk, Wv,
                                              Pp, Pq, Pk, PWq, PWk, PWv);
  qkv_mfma<<<dim3(18), dim3(256), 0, stream>>>(x3d, bq, bk, bv, PWq, PWk, PWv,
                                               Vm, QmH, QmT, PKt);
  x3d_tiles<<<dim3(LLEN*2), dim3(256), 0, stream>>>(x2d, bpre, ln_g, ln_b, beq, bek,
                                                    QmT, QmH, PKt, Pp, Pq, Pk, Sg, x2part);
  finish<<<dim3(LLEN), dim3(256), 0, stream>>>(Sg, x2part, Vm, Wo, bo, out);
}

// Round 7
// 247.147 us; speedup vs baseline: 2.1621x; 2.1621x over previous
//
#include <hip/hip_runtime.h>
#include <hip/hip_bf16.h>

#define LLEN 384
#define CDIM 256
#define NH 8
#define HD 32
#define DIN 128
#define LN_EPS 1e-5f
#define SCL 0.17677669529663687f   // 1/sqrt(32)

typedef __attribute__((ext_vector_type(8))) short bh8;
typedef __attribute__((ext_vector_type(4))) float f32x4;
typedef __attribute__((ext_vector_type(4))) unsigned int u32x4;

__device__ __forceinline__ unsigned short f2bf(float f){
  unsigned int u = __float_as_uint(f);
  u += 0x7fffu + ((u >> 16) & 1u);
  return (unsigned short)(u >> 16);
}

// Packed tree-reduce: sum v[0..7] over the 16 lanes of a quad (lane bits 0-3).
// Returns: lane lm holds full sum of v[lm&7].
__device__ __forceinline__ float pk_reduce8(const float* v, int lane){
  bool b0 = lane & 1, b1 = lane & 2, b2 = lane & 4;
  float r0 = (b0 ? v[1] : v[0]) + __shfl_xor(b0 ? v[0] : v[1], 1, 64);
  float r1 = (b0 ? v[3] : v[2]) + __shfl_xor(b0 ? v[2] : v[3], 1, 64);
  float r2 = (b0 ? v[5] : v[4]) + __shfl_xor(b0 ? v[4] : v[5], 1, 64);
  float r3 = (b0 ? v[7] : v[6]) + __shfl_xor(b0 ? v[6] : v[7], 1, 64);
  float s0 = (b1 ? r1 : r0) + __shfl_xor(b1 ? r0 : r1, 2, 64);
  float s1 = (b1 ? r3 : r2) + __shfl_xor(b1 ? r2 : r3, 2, 64);
  float t0 = (b2 ? s1 : s0) + __shfl_xor(b2 ? s0 : s1, 4, 64);
  return t0 + __shfl_xor(t0, 8, 64);
}

// ---------------------------------------------------------------------------
// Pack weights (fp32 row-major [K][N]) into bf16 MFMA B-fragment order.
// ---------------------------------------------------------------------------
__global__ __launch_bounds__(256) void pack_w(
    const float* __restrict__ Wpre, const float* __restrict__ Weq,
    const float* __restrict__ Wek,  const float* __restrict__ Wq,
    const float* __restrict__ Wk,   const float* __restrict__ Wv,
    unsigned short* __restrict__ Pp, unsigned short* __restrict__ Pq,
    unsigned short* __restrict__ Pk, unsigned short* __restrict__ PWq,
    unsigned short* __restrict__ PWk, unsigned short* __restrict__ PWv)
{
  int tid = blockIdx.x * 256 + threadIdx.x;   // 176 blocks * 256 = 45056
  const float* W; unsigned short* P; int base;
  if      (tid <  4096){ W = Wpre; P = Pp;  base = tid;         }
  else if (tid < 12288){ W = Weq;  P = Pq;  base = tid -  4096; }
  else if (tid < 20480){ W = Wek;  P = Pk;  base = tid - 12288; }
  else if (tid < 28672){ W = Wq;   P = PWq; base = tid - 20480; }
  else if (tid < 36864){ W = Wk;   P = PWk; base = tid - 28672; }
  else                 { W = Wv;   P = PWv; base = tid - 36864; }
  int l   = base & 63;
  int c   = (base >> 6) & 15;
  int kc  = base >> 10;
  int krow = kc*32 + (l >> 4)*8;
  int col  = c*16 + (l & 15);
  unsigned int wds[4];
  #pragma unroll
  for (int p = 0; p < 4; p++){
    unsigned short lo = f2bf(W[(size_t)(krow + 2*p    )*CDIM + col]);
    unsigned short hi = f2bf(W[(size_t)(krow + 2*p + 1)*CDIM + col]);
    wds[p] = (unsigned int)lo | ((unsigned int)hi << 16);
  }
  uint4 v; v.x = wds[0]; v.y = wds[1]; v.z = wds[2]; v.w = wds[3];
  *(uint4*)(P + (size_t)base*8) = v;
}

// ---------------------------------------------------------------------------
// qkv: 18 blocks (jb 0..5  x  m 0..2).
//  m=0: QmH (bf16 row-major) + QmT (fp32 transposed [c][j])
//  m=1: PKt  (K^T in MFMA B-frag layout, per head)
//  m=2: Vm (fp32 row-major)
// ---------------------------------------------------------------------------
__global__ __launch_bounds__(256) void qkv_mfma(
    const float* __restrict__ x3d,
    const float* __restrict__ bq, const float* __restrict__ bk, const float* __restrict__ bv,
    const unsigned short* __restrict__ PWq, const unsigned short* __restrict__ PWk,
    const unsigned short* __restrict__ PWv,
    float* __restrict__ Vm, unsigned short* __restrict__ QmH,
    float* __restrict__ QmT, unsigned short* __restrict__ PKt)
{
  __shared__ __align__(16) unsigned short Xb[64*264];
  const int bx = blockIdx.x;
  const int jb = bx / 3, m = bx % 3;
  const int t  = threadIdx.x;
  const int w  = t >> 6, l = t & 63, q4 = l >> 4, lm = l & 15;
  const int wbase = w << 6;

  const float* src = x3d + (size_t)jb*64*CDIM;
  #pragma unroll
  for (int it = 0; it < 16; it++){
    int idx = it*256 + t;
    int r = idx >> 6, k4 = (idx & 63) << 2;
    float4 v = *(const float4*)(src + (size_t)r*CDIM + k4);
    ushort4 b;
    b.x = f2bf(v.x); b.y = f2bf(v.y); b.z = f2bf(v.z); b.w = f2bf(v.w);
    *(ushort4*)(&Xb[r*264 + k4]) = b;
  }
  __syncthreads();

  const unsigned short* P = (m == 0) ? PWq : (m == 1) ? PWk : PWv;
  const float* bias       = (m == 0) ? bq  : (m == 1) ? bk  : bv;
  f32x4 acc[4][4];
  #pragma unroll
  for (int a = 0; a < 4; a++)
    #pragma unroll
    for (int b = 0; b < 4; b++){ f32x4 z = {0.f,0.f,0.f,0.f}; acc[a][b] = z; }
  #pragma unroll
  for (int kc = 0; kc < 8; kc++){
    bh8 af[4];
    #pragma unroll
    for (int rt = 0; rt < 4; rt++)
      af[rt] = *(const bh8*)(&Xb[(rt*16 + lm)*264 + kc*32 + q4*8]);
    #pragma unroll
    for (int ct = 0; ct < 4; ct++){
      bh8 bf = *(const bh8*)(P + ((size_t)(kc*16 + (w*4 + ct))*64 + l)*8);
      #pragma unroll
      for (int rt = 0; rt < 4; rt++)
        acc[rt][ct] = __builtin_amdgcn_mfma_f32_16x16x32_bf16(af[rt], bf, acc[rt][ct], 0, 0, 0);
    }
  }
  #pragma unroll
  for (int ct = 0; ct < 4; ct++){
    int c = wbase + ct*16 + lm;
    float bb = bias[c];
    #pragma unroll
    for (int rt = 0; rt < 4; rt++)
      #pragma unroll
      for (int rg = 0; rg < 4; rg++){
        int row = jb*64 + rt*16 + q4*4 + rg;
        float v = acc[rt][ct][rg] + bb;
        if (m == 0){
          QmH[(size_t)row*CDIM + c] = f2bf(v);
          QmT[(size_t)c*LLEN + row] = v;
        } else if (m == 1){
          int kc2 = c >> 5;            // head
          int jj2 = c & 7;
          int l2  = ((c >> 3) & 3)*16 + (row & 15);
          PKt[(((size_t)kc2*24 + (row >> 4))*64 + l2)*8 + jj2] = f2bf(v);
        } else {
          Vm[(size_t)row*CDIM + c] = v;
        }
      }
  }
}

// ---------------------------------------------------------------------------
// Main tile kernel: one block per (i, j-tile). 2304 blocks, 3 blocks/CU.
// R3 structure + explicit lookahead prefetch of global B-fragments so the
// ~200-cyc L2 latency hides under the previous kc-group's 16 MFMAs.
// ---------------------------------------------------------------------------
__global__ __launch_bounds__(256, 3) void x3d_tiles(
  const float* __restrict__ x2d,
  const float* __restrict__ bpre, const float* __restrict__ ln_g, const float* __restrict__ ln_b,
  const float* __restrict__ beq,  const float* __restrict__ bek,
  const float* __restrict__ QmT,  const unsigned short* __restrict__ QmH,
  const unsigned short* __restrict__ PKt,
  const unsigned short* __restrict__ Pp, const unsigned short* __restrict__ Pq,
  const unsigned short* __restrict__ Pk,
  float* __restrict__ Sg, float* __restrict__ x2part)
{
  __shared__ __align__(16) unsigned short EX[64*264];      // 33792 B
  __shared__ float rowstat[4][64][2];                      //  2048 B
  __shared__ float muS[64], istdS[64];                     //   512 B
  __shared__ float bpreS[CDIM], gS[CDIM], bSh[CDIM], beqS[CDIM], bekS[CDIM]; // 5120 B
  __shared__ float qk1S[NH*64];                            //  2048 B

  const int bx = blockIdx.x;
  const int i = bx / 6, jt = bx % 6, j0 = jt * 64;
  const int t = threadIdx.x;
  const int w = t >> 6, l = t & 63, q4 = l >> 4, lm = l & 15;
  const int wbase = w << 6;

  // ---- term1 via MFMA: batch all global loads, then the MFMA chain ----
  {
    bh8 kf[2][4], aqv[2];
    #pragma unroll
    for (int hh = 0; hh < 2; hh++){
      int h = 2*w + hh;
      aqv[hh] = *(const bh8*)(QmH + (size_t)i*CDIM + h*HD + q4*8);
      #pragma unroll
      for (int ct = 0; ct < 4; ct++)
        kf[hh][ct] = *(const bh8*)(PKt + (((size_t)h*24 + (jt*4 + ct))*64 + l)*8);
    }
    #pragma unroll
    for (int hh = 0; hh < 2; hh++){
      int h = 2*w + hh;
      #pragma unroll
      for (int ct = 0; ct < 4; ct++){
        f32x4 z = {0.f,0.f,0.f,0.f};
        f32x4 a1 = __builtin_amdgcn_mfma_f32_16x16x32_bf16(aqv[hh], kf[hh][ct], z, 0, 0, 0);
        if (q4 == 0) qk1S[h*64 + ct*16 + lm] = a1[0];
      }
    }
  }

  bpreS[t] = bpre[t]; gS[t] = ln_g[t]; bSh[t] = ln_b[t];
  beqS[t]  = beq[t];  bekS[t] = bek[t];

  // ---- stage x2d tile (64 x 128) as bf16, stride 136 (non-temporal) ----
  {
    const float* src = x2d + ((size_t)i*LLEN + j0)*DIN;
    #pragma unroll
    for (int it = 0; it < 8; it++){
      int r  = it*8 + (t >> 5);
      int k4 = (t & 31)*4;
      u32x4 uv = __builtin_nontemporal_load((const u32x4*)(src + (size_t)r*DIN + k4));
      ushort4 b;
      b.x = f2bf(__uint_as_float(uv.x)); b.y = f2bf(__uint_as_float(uv.y));
      b.z = f2bf(__uint_as_float(uv.z)); b.w = f2bf(__uint_as_float(uv.w));
      *(ushort4*)(&EX[r*136 + k4]) = b;
    }
  }
  __syncthreads();

  // ---- GEMM1: Epre = X @ Wpre (wf lookahead) ----
  f32x4 acc[4][4];
  #pragma unroll
  for (int a = 0; a < 4; a++)
    #pragma unroll
    for (int b = 0; b < 4; b++){ f32x4 z = {0.f,0.f,0.f,0.f}; acc[a][b] = z; }
  {
    bh8 wc[4], wn[4];
    #pragma unroll
    for (int ct = 0; ct < 4; ct++)
      wc[ct] = *(const bh8*)(Pp + ((size_t)(w*4 + ct)*64 + l)*8);
    #pragma unroll
    for (int kc = 0; kc < 4; kc++){
      if (kc < 3)
        #pragma unroll
        for (int ct = 0; ct < 4; ct++)
          wn[ct] = *(const bh8*)(Pp + ((size_t)((kc+1)*16 + (w*4 + ct))*64 + l)*8);
      bh8 af[4];
      #pragma unroll
      for (int rt = 0; rt < 4; rt++)
        af[rt] = *(const bh8*)(&EX[(rt*16 + lm)*136 + kc*32 + q4*8]);
      #pragma unroll
      for (int ct = 0; ct < 4; ct++)
        #pragma unroll
        for (int rt = 0; rt < 4; rt++)
          acc[rt][ct] = __builtin_amdgcn_mfma_f32_16x16x32_bf16(af[rt], wc[ct], acc[rt][ct], 0, 0, 0);
      #pragma unroll
      for (int ct = 0; ct < 4; ct++) wc[ct] = wn[ct];
    }
  }

  // ---- + bpre, per-row LN stats via packed tree-reduce ----
  #pragma unroll
  for (int rt = 0; rt < 4; rt++){
    float v[8];
    #pragma unroll
    for (int p = 0; p < 8; p++) v[p] = 0.f;
    #pragma unroll
    for (int ct = 0; ct < 4; ct++){
      float bb = bpreS[wbase + ct*16 + lm];
      #pragma unroll
      for (int rg = 0; rg < 4; rg++){
        float x = acc[rt][ct][rg] + bb;
        acc[rt][ct][rg] = x;
        v[2*rg]   += x;
        v[2*rg+1] += x*x;
      }
    }
    float red = pk_reduce8(v, lm);
    if (lm < 8){
      int p = lm;
      rowstat[w][rt*16 + q4*4 + (p >> 1)][p & 1] = red;
    }
  }
  __syncthreads();
  if (t < 64){
    float s  = rowstat[0][t][0] + rowstat[1][t][0] + rowstat[2][t][0] + rowstat[3][t][0];
    float s2 = rowstat[0][t][1] + rowstat[1][t][1] + rowstat[2][t][1] + rowstat[3][t][1];
    float mu = s * (1.f/256.f);
    float var = s2 * (1.f/256.f) - mu*mu;
    muS[t] = mu;
    istdS[t] = rsqrtf(var + LN_EPS);
  }
  __syncthreads();

  // ---- LN + ReLU -> bf16 E tile (stride 264) ----
  #pragma unroll
  for (int rt = 0; rt < 4; rt++){
    #pragma unroll
    for (int rg = 0; rg < 4; rg++){
      int row = rt*16 + q4*4 + rg;
      float mu = muS[row], is = istdS[row];
      #pragma unroll
      for (int ct = 0; ct < 4; ct++){
        int c = wbase + ct*16 + lm;
        float v = (acc[rt][ct][rg] - mu)*is*gS[c] + bSh[c];
        v = fmaxf(v, 0.f);
        EX[row*264 + c] = f2bf(v);
      }
    }
  }
  __syncthreads();

  // ---- GEMM2: EFK = E @ Wek (wf lookahead) ----
  #pragma unroll
  for (int a = 0; a < 4; a++)
    #pragma unroll
    for (int b = 0; b < 4; b++){ f32x4 z = {0.f,0.f,0.f,0.f}; acc[a][b] = z; }
  {
    bh8 wc[4], wn[4];
    #pragma unroll
    for (int ct = 0; ct < 4; ct++)
      wc[ct] = *(const bh8*)(Pk + ((size_t)(w*4 + ct)*64 + l)*8);
    #pragma unroll
    for (int kc = 0; kc < 8; kc++){
      if (kc < 7)
        #pragma unroll
        for (int ct = 0; ct < 4; ct++)
          wn[ct] = *(const bh8*)(Pk + ((size_t)((kc+1)*16 + (w*4 + ct))*64 + l)*8);
      bh8 af[4];
      #pragma unroll
      for (int rt = 0; rt < 4; rt++)
        af[rt] = *(const bh8*)(&EX[(rt*16 + lm)*264 + kc*32 + q4*8]);
      #pragma unroll
      for (int ct = 0; ct < 4; ct++)
        #pragma unroll
        for (int rt = 0; rt < 4; rt++)
          acc[rt][ct] = __builtin_amdgcn_mfma_f32_16x16x32_bf16(af[rt], wc[ct], acc[rt][ct], 0, 0, 0);
      #pragma unroll
      for (int ct = 0; ct < 4; ct++) wc[ct] = wn[ct];
    }
  }

  // ---- scores: term2 packed-reduce + qk1 + scale (qv one-rt lookahead) ----
  float screg[4];
  {
    f32x4 qvc[4], qvn[4];
    #pragma unroll
    for (int ct = 0; ct < 4; ct++){
      int c = wbase + ct*16 + lm;
      qvc[ct] = *(const f32x4*)(QmT + (size_t)c*LLEN + j0 + q4*4);
    }
    #pragma unroll
    for (int rt = 0; rt < 4; rt++){
      if (rt < 3)
        #pragma unroll
        for (int ct = 0; ct < 4; ct++){
          int c = wbase + ct*16 + lm;
          qvn[ct] = *(const f32x4*)(QmT + (size_t)c*LLEN + j0 + (rt+1)*16 + q4*4);
        }
      float v[8];
      #pragma unroll
      for (int p = 0; p < 8; p++) v[p] = 0.f;
      #pragma unroll
      for (int ct = 0; ct < 4; ct++){
        float bek_ = bekS[wbase + ct*16 + lm];
        int wh = ct >> 1;
        v[0 + wh] += (acc[rt][ct][0] + bek_) * qvc[ct][0];
        v[2 + wh] += (acc[rt][ct][1] + bek_) * qvc[ct][1];
        v[4 + wh] += (acc[rt][ct][2] + bek_) * qvc[ct][2];
        v[6 + wh] += (acc[rt][ct][3] + bek_) * qvc[ct][3];
      }
      float red = pk_reduce8(v, lm);
      int p = lm & 7;
      int jloc = rt*16 + q4*4 + (p >> 1);
      float sc = (red + qk1S[(2*w + (p & 1))*64 + jloc]) * SCL;
      screg[rt] = sc;
      if (lm < 8)
        Sg[((size_t)i*NH + 2*w + (p & 1))*LLEN + j0 + jloc] = sc;
      #pragma unroll
      for (int ct = 0; ct < 4; ct++) qvc[ct] = qvn[ct];
    }
  }

  // ---- GEMM3: EFQ = E @ Weq (wf lookahead) ----
  #pragma unroll
  for (int a = 0; a < 4; a++)
    #pragma unroll
    for (int b = 0; b < 4; b++){ f32x4 z = {0.f,0.f,0.f,0.f}; acc[a][b] = z; }
  {
    bh8 wc[4], wn[4];
    #pragma unroll
    for (int ct = 0; ct < 4; ct++)
      wc[ct] = *(const bh8*)(Pq + ((size_t)(w*4 + ct)*64 + l)*8);
    #pragma unroll
    for (int kc = 0; kc < 8; kc++){
      if (kc < 7)
        #pragma unroll
        for (int ct = 0; ct < 4; ct++)
          wn[ct] = *(const bh8*)(Pq + ((size_t)((kc+1)*16 + (w*4 + ct))*64 + l)*8);
      bh8 af[4];
      #pragma unroll
      for (int rt = 0; rt < 4; rt++)
        af[rt] = *(const bh8*)(&EX[(rt*16 + lm)*264 + kc*32 + q4*8]);
      #pragma unroll
      for (int ct = 0; ct < 4; ct++)
        #pragma unroll
        for (int rt = 0; rt < 4; rt++)
          acc[rt][ct] = __builtin_amdgcn_mfma_f32_16x16x32_bf16(af[rt], wc[ct], acc[rt][ct], 0, 0, 0);
      #pragma unroll
      for (int ct = 0; ct < 4; ct++) wc[ct] = wn[ct];
    }
  }

  // ---- x2 partials: x2[h,c] += s[h,j]*efq[j,c] (pre-softmax scaled) ----
  float x2p[4] = {0.f, 0.f, 0.f, 0.f};
  float bq4[4];
  #pragma unroll
  for (int ct = 0; ct < 4; ct++) bq4[ct] = beqS[wbase + ct*16 + lm];
  #pragma unroll
  for (int rt = 0; rt < 4; rt++){
    float sb[8];
    #pragma unroll
    for (int p = 0; p < 8; p++)
      sb[p] = __shfl(screg[rt], (l & 48) | p, 64);
    #pragma unroll
    for (int ct = 0; ct < 4; ct++){
      int wh = ct >> 1;
      #pragma unroll
      for (int rg = 0; rg < 4; rg++)
        x2p[ct] = fmaf(sb[2*rg + wh], acc[rt][ct][rg] + bq4[ct], x2p[ct]);
    }
  }
  {
    bool b4 = l & 16, b5 = l & 32;
    float r0 = (b4 ? x2p[1] : x2p[0]) + __shfl_xor(b4 ? x2p[0] : x2p[1], 16, 64);
    float r1 = (b4 ? x2p[3] : x2p[2]) + __shfl_xor(b4 ? x2p[2] : x2p[3], 16, 64);
    float q  = (b5 ? r1 : r0) + __shfl_xor(b5 ? r0 : r1, 32, 64);
    int ctq = ((l >> 4) & 1) | (((l >> 5) & 1) << 1);
    x2part[((size_t)jt*LLEN + i)*CDIM + wbase + ctq*16 + lm] = q;
  }
}

// ---------------------------------------------------------------------------
// finish: softmax + x1 + x2 + out-proj. 384 blocks.
// ---------------------------------------------------------------------------
__global__ __launch_bounds__(256) void finish(
    const float* __restrict__ Sg, const float* __restrict__ x2part,
    const float* __restrict__ Vm, const float* __restrict__ Wo,
    const float* __restrict__ bo, float* __restrict__ out)
{
  __shared__ float scoresS[NH*LLEN];   // 12 KB
  __shared__ float xoutS[CDIM];
  const int i = blockIdx.x;
  const int t = threadIdx.x;

  #pragma unroll
  for (int it = 0; it < 3; it++)
    ((float4*)scoresS)[it*256 + t] = ((const float4*)(Sg + (size_t)i*NH*LLEN))[it*256 + t];
  __syncthreads();

  const int h = t >> 5;
  const int g32 = t & 31;
  float sv[12];
  float mx = -3.0e38f;
  #pragma unroll
  for (int it = 0; it < 12; it++){
    float s = scoresS[h*LLEN + it*32 + g32];
    sv[it] = s;
    mx = fmaxf(mx, s);
  }
  #pragma unroll
  for (int mk = 1; mk < 32; mk <<= 1) mx = fmaxf(mx, __shfl_xor(mx, mk, 64));
  float den = 0.f;
  #pragma unroll
  for (int it = 0; it < 12; it++){ float e = __expf(sv[it] - mx); sv[it] = e; den += e; }
  #pragma unroll
  for (int mk = 1; mk < 32; mk <<= 1) den += __shfl_xor(den, mk, 64);
  float rden = 1.f / den;
  #pragma unroll
  for (int it = 0; it < 12; it++) scoresS[h*LLEN + it*32 + g32] = sv[it]*rden;
  __syncthreads();

  float a0 = 0.f, a1 = 0.f, a2 = 0.f, a3 = 0.f;
  {
    const float* vp = Vm + t;
    const float* sp = scoresS + h*LLEN;
    #pragma unroll 4
    for (int j = 0; j < LLEN; j += 4){
      a0 = fmaf(sp[j+0], vp[(size_t)(j+0)*CDIM], a0);
      a1 = fmaf(sp[j+1], vp[(size_t)(j+1)*CDIM], a1);
      a2 = fmaf(sp[j+2], vp[(size_t)(j+2)*CDIM], a2);
      a3 = fmaf(sp[j+3], vp[(size_t)(j+3)*CDIM], a3);
    }
  }
  float x2v = 0.f;
  #pragma unroll
  for (int jt = 0; jt < 6; jt++)
    x2v += x2part[((size_t)jt*LLEN + i)*CDIM + t];
  xoutS[t] = (a0 + a1) + (a2 + a3) + x2v;
  __syncthreads();

  float b0a = bo[t], b1a = 0.f, b2a = 0.f, b3a = 0.f;
  #pragma unroll 4
  for (int c = 0; c < CDIM; c += 4){
    b0a = fmaf(xoutS[c+0], Wo[(size_t)(c+0)*CDIM + t], b0a);
    b1a = fmaf(xoutS[c+1], Wo[(size_t)(c+1)*CDIM + t], b1a);
    b2a = fmaf(xoutS[c+2], Wo[(size_t)(c+2)*CDIM + t], b2a);
    b3a = fmaf(xoutS[c+3], Wo[(size_t)(c+3)*CDIM + t], b3a);
  }
  out[(size_t)i*CDIM + t] = (b0a + b1a) + (b2a + b3a);
}

// ---------------------------------------------------------------------------
extern "C" void kernel_launch(void* const* d_in, const int* in_sizes, int n_in,
                              void* d_out, int out_size, void* d_ws, size_t ws_size,
                              hipStream_t stream)
{
  const float* x2d  = (const float*)d_in[0];
  const float* x3d  = (const float*)d_in[1];
  const float* Wq   = (const float*)d_in[2];
  const float* bq   = (const float*)d_in[3];
  const float* Wk   = (const float*)d_in[4];
  const float* bk   = (const float*)d_in[5];
  const float* Wv   = (const float*)d_in[6];
  const float* bv   = (const float*)d_in[7];
  const float* Wpre = (const float*)d_in[8];
  const float* bpre = (const float*)d_in[9];
  const float* ln_g = (const float*)d_in[10];
  const float* ln_b = (const float*)d_in[11];
  const float* Weq  = (const float*)d_in[12];
  const float* beq  = (const float*)d_in[13];
  const float* Wek  = (const float*)d_in[14];
  const float* bek  = (const float*)d_in[15];
  const float* Wo   = (const float*)d_in[16];
  const float* bo   = (const float*)d_in[17];
  float* out = (float*)d_out;

  float* Vm  = (float*)d_ws;                                 // 384*256 f32
  float* QmT = Vm + LLEN*CDIM;                               // 256*384 f32
  unsigned short* QmH = (unsigned short*)(QmT + CDIM*LLEN);  // 384*256 bf16
  unsigned short* PKt = QmH + LLEN*CDIM;                     // 8*24*64*8 bf16
  unsigned short* Pp  = PKt + LLEN*CDIM;                     // 128*256
  unsigned short* Pq  = Pp  + DIN*CDIM;                      // 256*256
  unsigned short* Pk  = Pq  + CDIM*CDIM;
  unsigned short* PWq = Pk  + CDIM*CDIM;
  unsigned short* PWk = PWq + CDIM*CDIM;
  unsigned short* PWv = PWk + CDIM*CDIM;
  float* Sg     = (float*)(PWv + CDIM*CDIM);                 // 384*8*384 f32
  float* x2part = Sg + (size_t)LLEN*NH*LLEN;                 // 6*384*256 f32

  pack_w<<<dim3(176), dim3(256), 0, stream>>>(Wpre, Weq, Wek, Wq, Wk, Wv,
                                              Pp, Pq, Pk, PWq, PWk, PWv);
  qkv_mfma<<<dim3(18), dim3(256), 0, stream>>>(x3d, bq, bk, bv, PWq, PWk, PWv,
                                               Vm, QmH, QmT, PKt);
  x3d_tiles<<<dim3(LLEN*6), dim3(256), 0, stream>>>(x2d, bpre, ln_g, ln_b, beq, bek,
                                                    QmT, QmH, PKt, Pp, Pq, Pk, Sg, x2part);
  finish<<<dim3(LLEN), dim3(256), 0, stream>>>(Sg, x2part, Vm, Wo, bo, out);
}

// Round 8
// 229.297 us; speedup vs baseline: 2.3304x; 1.0779x over previous
//
#include <hip/hip_runtime.h>
#include <hip/hip_bf16.h>

#define LLEN 384
#define CDIM 256
#define NH 8
#define HD 32
#define DIN 128
#define LN_EPS 1e-5f
#define SCL 0.17677669529663687f   // 1/sqrt(32)

typedef __attribute__((ext_vector_type(8))) short bh8;
typedef __attribute__((ext_vector_type(4))) float f32x4;
typedef __attribute__((ext_vector_type(4))) unsigned int u32x4;

__device__ __forceinline__ unsigned short f2bf(float f){
  unsigned int u = __float_as_uint(f);
  u += 0x7fffu + ((u >> 16) & 1u);
  return (unsigned short)(u >> 16);
}

// Packed tree-reduce: sum v[0..7] over the 16 lanes of a quad (lane bits 0-3).
// Returns: lane lm holds full sum of v[lm&7].
__device__ __forceinline__ float pk_reduce8(const float* v, int lane){
  bool b0 = lane & 1, b1 = lane & 2, b2 = lane & 4;
  float r0 = (b0 ? v[1] : v[0]) + __shfl_xor(b0 ? v[0] : v[1], 1, 64);
  float r1 = (b0 ? v[3] : v[2]) + __shfl_xor(b0 ? v[2] : v[3], 1, 64);
  float r2 = (b0 ? v[5] : v[4]) + __shfl_xor(b0 ? v[4] : v[5], 1, 64);
  float r3 = (b0 ? v[7] : v[6]) + __shfl_xor(b0 ? v[6] : v[7], 1, 64);
  float s0 = (b1 ? r1 : r0) + __shfl_xor(b1 ? r0 : r1, 2, 64);
  float s1 = (b1 ? r3 : r2) + __shfl_xor(b1 ? r2 : r3, 2, 64);
  float t0 = (b2 ? s1 : s0) + __shfl_xor(b2 ? s0 : s1, 4, 64);
  return t0 + __shfl_xor(t0, 8, 64);
}

// ---------------------------------------------------------------------------
// Pack weights (fp32 row-major [K][N]) into bf16 MFMA B-fragment order.
// ---------------------------------------------------------------------------
__global__ __launch_bounds__(256) void pack_w(
    const float* __restrict__ Wpre, const float* __restrict__ Weq,
    const float* __restrict__ Wek,  const float* __restrict__ Wq,
    const float* __restrict__ Wk,   const float* __restrict__ Wv,
    unsigned short* __restrict__ Pp, unsigned short* __restrict__ Pq,
    unsigned short* __restrict__ Pk, unsigned short* __restrict__ PWq,
    unsigned short* __restrict__ PWk, unsigned short* __restrict__ PWv)
{
  int tid = blockIdx.x * 256 + threadIdx.x;   // 176 blocks * 256 = 45056
  const float* W; unsigned short* P; int base;
  if      (tid <  4096){ W = Wpre; P = Pp;  base = tid;         }
  else if (tid < 12288){ W = Weq;  P = Pq;  base = tid -  4096; }
  else if (tid < 20480){ W = Wek;  P = Pk;  base = tid - 12288; }
  else if (tid < 28672){ W = Wq;   P = PWq; base = tid - 20480; }
  else if (tid < 36864){ W = Wk;   P = PWk; base = tid - 28672; }
  else                 { W = Wv;   P = PWv; base = tid - 36864; }
  int l   = base & 63;
  int c   = (base >> 6) & 15;
  int kc  = base >> 10;
  int krow = kc*32 + (l >> 4)*8;
  int col  = c*16 + (l & 15);
  unsigned int wds[4];
  #pragma unroll
  for (int p = 0; p < 4; p++){
    unsigned short lo = f2bf(W[(size_t)(krow + 2*p    )*CDIM + col]);
    unsigned short hi = f2bf(W[(size_t)(krow + 2*p + 1)*CDIM + col]);
    wds[p] = (unsigned int)lo | ((unsigned int)hi << 16);
  }
  uint4 v; v.x = wds[0]; v.y = wds[1]; v.z = wds[2]; v.w = wds[3];
  *(uint4*)(P + (size_t)base*8) = v;
}

// ---------------------------------------------------------------------------
// qkv: 72 blocks = jb(6) x m(3) x nq(4). Each wave owns one 16-col chunk.
//  m=0: QmH (bf16 row-major) + QmT (fp32 transposed [c][j])
//  m=1: PKt  (K^T in MFMA B-frag layout, per head)
//  m=2: Vm (fp32 row-major)
// ---------------------------------------------------------------------------
__global__ __launch_bounds__(256) void qkv_mfma(
    const float* __restrict__ x3d,
    const float* __restrict__ bq, const float* __restrict__ bk, const float* __restrict__ bv,
    const unsigned short* __restrict__ PWq, const unsigned short* __restrict__ PWk,
    const unsigned short* __restrict__ PWv,
    float* __restrict__ Vm, unsigned short* __restrict__ QmH,
    float* __restrict__ QmT, unsigned short* __restrict__ PKt)
{
  __shared__ __align__(16) unsigned short Xb[64*264];
  const int bx = blockIdx.x;
  const int jb = bx / 12, rem = bx % 12;
  const int m = rem >> 2, nq = rem & 3;
  const int t  = threadIdx.x;
  const int w  = t >> 6, l = t & 63, q4 = l >> 4, lm = l & 15;

  const float* src = x3d + (size_t)jb*64*CDIM;
  #pragma unroll
  for (int it = 0; it < 16; it++){
    int idx = it*256 + t;
    int r = idx >> 6, k4 = (idx & 63) << 2;
    float4 v = *(const float4*)(src + (size_t)r*CDIM + k4);
    ushort4 b;
    b.x = f2bf(v.x); b.y = f2bf(v.y); b.z = f2bf(v.z); b.w = f2bf(v.w);
    *(ushort4*)(&Xb[r*264 + k4]) = b;
  }
  __syncthreads();

  const unsigned short* P = (m == 0) ? PWq : (m == 1) ? PWk : PWv;
  const float* bias       = (m == 0) ? bq  : (m == 1) ? bk  : bv;
  const int cidx = nq*4 + w;          // 16-col chunk this wave owns
  f32x4 acc[4];
  #pragma unroll
  for (int a = 0; a < 4; a++){ f32x4 z = {0.f,0.f,0.f,0.f}; acc[a] = z; }
  #pragma unroll
  for (int kc = 0; kc < 8; kc++){
    bh8 bf = *(const bh8*)(P + ((size_t)(kc*16 + cidx)*64 + l)*8);
    #pragma unroll
    for (int rt = 0; rt < 4; rt++){
      bh8 af = *(const bh8*)(&Xb[(rt*16 + lm)*264 + kc*32 + q4*8]);
      acc[rt] = __builtin_amdgcn_mfma_f32_16x16x32_bf16(af, bf, acc[rt], 0, 0, 0);
    }
  }
  {
    int c = cidx*16 + lm;
    float bb = bias[c];
    #pragma unroll
    for (int rt = 0; rt < 4; rt++)
      #pragma unroll
      for (int rg = 0; rg < 4; rg++){
        int row = jb*64 + rt*16 + q4*4 + rg;
        float v = acc[rt][rg] + bb;
        if (m == 0){
          QmH[(size_t)row*CDIM + c] = f2bf(v);
          QmT[(size_t)c*LLEN + row] = v;
        } else if (m == 1){
          int kc2 = c >> 5;            // head
          int jj2 = c & 7;
          int l2  = ((c >> 3) & 3)*16 + (row & 15);
          PKt[(((size_t)kc2*24 + (row >> 4))*64 + l2)*8 + jj2] = f2bf(v);
        } else {
          Vm[(size_t)row*CDIM + c] = v;
        }
      }
  }
}

// ---------------------------------------------------------------------------
// Main tile kernel: one block per (i, j-tile). 2304 blocks. (R3 structure —
// empirically best across R4-R7 variants; do not "optimize" the epilogues.)
// ---------------------------------------------------------------------------
__global__ __launch_bounds__(256, 3) void x3d_tiles(
  const float* __restrict__ x2d,
  const float* __restrict__ bpre, const float* __restrict__ ln_g, const float* __restrict__ ln_b,
  const float* __restrict__ beq,  const float* __restrict__ bek,
  const float* __restrict__ QmT,  const unsigned short* __restrict__ QmH,
  const unsigned short* __restrict__ PKt,
  const unsigned short* __restrict__ Pp, const unsigned short* __restrict__ Pq,
  const unsigned short* __restrict__ Pk,
  float* __restrict__ Sg, float* __restrict__ x2part)
{
  __shared__ __align__(16) unsigned short EX[64*264];      // 33792 B
  __shared__ float rowstat[4][64][2];                      //  2048 B
  __shared__ float muS[64], istdS[64];                     //   512 B
  __shared__ float bpreS[CDIM], gS[CDIM], bSh[CDIM], beqS[CDIM], bekS[CDIM]; // 5120 B
  __shared__ float qk1S[NH*64];                            //  2048 B

  const int bx = blockIdx.x;
  const int i = bx / 6, jt = bx % 6, j0 = jt * 64;
  const int t = threadIdx.x;
  const int w = t >> 6, l = t & 63, q4 = l >> 4, lm = l & 15;
  const int wbase = w << 6;

  // ---- term1 via MFMA: qk1[h][j] = q_i(h).k_j(h); wave w does heads 2w,2w+1
  {
    #pragma unroll
    for (int hh = 0; hh < 2; hh++){
      int h = 2*w + hh;
      bh8 aq = *(const bh8*)(QmH + (size_t)i*CDIM + h*HD + q4*8);
      #pragma unroll
      for (int ct = 0; ct < 4; ct++){
        bh8 bf = *(const bh8*)(PKt + (((size_t)h*24 + (jt*4 + ct))*64 + l)*8);
        f32x4 z = {0.f,0.f,0.f,0.f};
        f32x4 a1 = __builtin_amdgcn_mfma_f32_16x16x32_bf16(aq, bf, z, 0, 0, 0);
        if (q4 == 0) qk1S[h*64 + ct*16 + lm] = a1[0];
      }
    }
  }

  bpreS[t] = bpre[t]; gS[t] = ln_g[t]; bSh[t] = ln_b[t];
  beqS[t]  = beq[t];  bekS[t] = bek[t];

  // ---- stage x2d tile (64 x 128) as bf16, stride 136 (non-temporal) ----
  {
    const float* src = x2d + ((size_t)i*LLEN + j0)*DIN;
    #pragma unroll
    for (int it = 0; it < 8; it++){
      int r  = it*8 + (t >> 5);
      int k4 = (t & 31)*4;
      u32x4 uv = __builtin_nontemporal_load((const u32x4*)(src + (size_t)r*DIN + k4));
      ushort4 b;
      b.x = f2bf(__uint_as_float(uv.x)); b.y = f2bf(__uint_as_float(uv.y));
      b.z = f2bf(__uint_as_float(uv.z)); b.w = f2bf(__uint_as_float(uv.w));
      *(ushort4*)(&EX[r*136 + k4]) = b;
    }
  }
  __syncthreads();

  // ---- GEMM1: Epre = X @ Wpre ----
  f32x4 acc[4][4];
  #pragma unroll
  for (int a = 0; a < 4; a++)
    #pragma unroll
    for (int b = 0; b < 4; b++){ f32x4 z = {0.f,0.f,0.f,0.f}; acc[a][b] = z; }
  #pragma unroll
  for (int kc = 0; kc < 4; kc++){
    bh8 af[4];
    #pragma unroll
    for (int rt = 0; rt < 4; rt++)
      af[rt] = *(const bh8*)(&EX[(rt*16 + lm)*136 + kc*32 + q4*8]);
    #pragma unroll
    for (int ct = 0; ct < 4; ct++){
      bh8 bf = *(const bh8*)(Pp + ((size_t)(kc*16 + (w*4 + ct))*64 + l)*8);
      #pragma unroll
      for (int rt = 0; rt < 4; rt++)
        acc[rt][ct] = __builtin_amdgcn_mfma_f32_16x16x32_bf16(af[rt], bf, acc[rt][ct], 0, 0, 0);
    }
  }

  // ---- + bpre, per-row LN stats via packed tree-reduce ----
  #pragma unroll
  for (int rt = 0; rt < 4; rt++){
    float v[8];   // v[2rg+0]=sum partial, v[2rg+1]=sq partial
    #pragma unroll
    for (int p = 0; p < 8; p++) v[p] = 0.f;
    #pragma unroll
    for (int ct = 0; ct < 4; ct++){
      float bb = bpreS[wbase + ct*16 + lm];
      #pragma unroll
      for (int rg = 0; rg < 4; rg++){
        float x = acc[rt][ct][rg] + bb;
        acc[rt][ct][rg] = x;
        v[2*rg]   += x;
        v[2*rg+1] += x*x;
      }
    }
    float red = pk_reduce8(v, lm);
    if (lm < 8){
      int p = lm;                       // p = 2rg+which
      rowstat[w][rt*16 + q4*4 + (p >> 1)][p & 1] = red;
    }
  }
  __syncthreads();
  if (t < 64){
    float s  = rowstat[0][t][0] + rowstat[1][t][0] + rowstat[2][t][0] + rowstat[3][t][0];
    float s2 = rowstat[0][t][1] + rowstat[1][t][1] + rowstat[2][t][1] + rowstat[3][t][1];
    float mu = s * (1.f/256.f);
    float var = s2 * (1.f/256.f) - mu*mu;
    muS[t] = mu;
    istdS[t] = rsqrtf(var + LN_EPS);
  }
  __syncthreads();

  // ---- LN + ReLU -> bf16 E tile (stride 264) ----
  #pragma unroll
  for (int rt = 0; rt < 4; rt++){
    #pragma unroll
    for (int rg = 0; rg < 4; rg++){
      int row = rt*16 + q4*4 + rg;
      float mu = muS[row], is = istdS[row];
      #pragma unroll
      for (int ct = 0; ct < 4; ct++){
        int c = wbase + ct*16 + lm;
        float v = (acc[rt][ct][rg] - mu)*is*gS[c] + bSh[c];
        v = fmaxf(v, 0.f);
        EX[row*264 + c] = f2bf(v);
      }
    }
  }
  __syncthreads();

  // ---- GEMM2: EFK = E @ Wek ----
  #pragma unroll
  for (int a = 0; a < 4; a++)
    #pragma unroll
    for (int b = 0; b < 4; b++){ f32x4 z = {0.f,0.f,0.f,0.f}; acc[a][b] = z; }
  #pragma unroll
  for (int kc = 0; kc < 8; kc++){
    bh8 af[4];
    #pragma unroll
    for (int rt = 0; rt < 4; rt++)
      af[rt] = *(const bh8*)(&EX[(rt*16 + lm)*264 + kc*32 + q4*8]);
    #pragma unroll
    for (int ct = 0; ct < 4; ct++){
      bh8 bf = *(const bh8*)(Pk + ((size_t)(kc*16 + (w*4 + ct))*64 + l)*8);
      #pragma unroll
      for (int rt = 0; rt < 4; rt++)
        acc[rt][ct] = __builtin_amdgcn_mfma_f32_16x16x32_bf16(af[rt], bf, acc[rt][ct], 0, 0, 0);
    }
  }

  // ---- scores: term2 packed-reduce + qk1 + scale; keep in screg ----
  float screg[4];
  #pragma unroll
  for (int rt = 0; rt < 4; rt++){
    float v[8];   // v[2rg+which]
    #pragma unroll
    for (int p = 0; p < 8; p++) v[p] = 0.f;
    #pragma unroll
    for (int ct = 0; ct < 4; ct++){
      int c = wbase + ct*16 + lm;
      float bek_ = bekS[c];
      float4 qv = *(const float4*)(QmT + (size_t)c*LLEN + j0 + rt*16 + q4*4);
      int wh = ct >> 1;
      v[0 + wh] += (acc[rt][ct][0] + bek_) * qv.x;
      v[2 + wh] += (acc[rt][ct][1] + bek_) * qv.y;
      v[4 + wh] += (acc[rt][ct][2] + bek_) * qv.z;
      v[6 + wh] += (acc[rt][ct][3] + bek_) * qv.w;
    }
    float red = pk_reduce8(v, lm);
    int p = lm & 7;                     // p = 2rg + which
    int jloc = rt*16 + q4*4 + (p >> 1);
    float sc = (red + qk1S[(2*w + (p & 1))*64 + jloc]) * SCL;
    screg[rt] = sc;
    if (lm < 8)
      Sg[((size_t)i*NH + 2*w + (p & 1))*LLEN + j0 + jloc] = sc;
  }

  // ---- GEMM3: EFQ = E @ Weq ----
  #pragma unroll
  for (int a = 0; a < 4; a++)
    #pragma unroll
    for (int b = 0; b < 4; b++){ f32x4 z = {0.f,0.f,0.f,0.f}; acc[a][b] = z; }
  #pragma unroll
  for (int kc = 0; kc < 8; kc++){
    bh8 af[4];
    #pragma unroll
    for (int rt = 0; rt < 4; rt++)
      af[rt] = *(const bh8*)(&EX[(rt*16 + lm)*264 + kc*32 + q4*8]);
    #pragma unroll
    for (int ct = 0; ct < 4; ct++){
      bh8 bf = *(const bh8*)(Pq + ((size_t)(kc*16 + (w*4 + ct))*64 + l)*8);
      #pragma unroll
      for (int rt = 0; rt < 4; rt++)
        acc[rt][ct] = __builtin_amdgcn_mfma_f32_16x16x32_bf16(af[rt], bf, acc[rt][ct], 0, 0, 0);
    }
  }

  // ---- x2 partial: x2[h,c] += scores[h,j]*efq[j,c] (pre-softmax scaled) ----
  float x2p[4] = {0.f, 0.f, 0.f, 0.f};
  float bq4[4];
  #pragma unroll
  for (int ct = 0; ct < 4; ct++) bq4[ct] = beqS[wbase + ct*16 + lm];
  #pragma unroll
  for (int rt = 0; rt < 4; rt++){
    float sb[8];
    #pragma unroll
    for (int p = 0; p < 8; p++)
      sb[p] = __shfl(screg[rt], (l & 48) | p, 64);
    #pragma unroll
    for (int ct = 0; ct < 4; ct++){
      int wh = ct >> 1;
      #pragma unroll
      for (int rg = 0; rg < 4; rg++)
        x2p[ct] = fmaf(sb[2*rg + wh], acc[rt][ct][rg] + bq4[ct], x2p[ct]);
    }
  }
  {
    bool b4 = l & 16, b5 = l & 32;
    float r0 = (b4 ? x2p[1] : x2p[0]) + __shfl_xor(b4 ? x2p[0] : x2p[1], 16, 64);
    float r1 = (b4 ? x2p[3] : x2p[2]) + __shfl_xor(b4 ? x2p[2] : x2p[3], 16, 64);
    float q  = (b5 ? r1 : r0) + __shfl_xor(b5 ? r0 : r1, 32, 64);
    int ctq = ((l >> 4) & 1) | (((l >> 5) & 1) << 1);
    x2part[((size_t)jt*LLEN + i)*CDIM + wbase + ctq*16 + lm] = q;
  }
}

// ---------------------------------------------------------------------------
// finish: softmax + x1 + x2 + out-proj. 384 blocks. x1 with 8-deep ILP.
// ---------------------------------------------------------------------------
__global__ __launch_bounds__(256) void finish(
    const float* __restrict__ Sg, const float* __restrict__ x2part,
    const float* __restrict__ Vm, const float* __restrict__ Wo,
    const float* __restrict__ bo, float* __restrict__ out)
{
  __shared__ float scoresS[NH*LLEN];   // 12 KB
  __shared__ float xoutS[CDIM];
  const int i = blockIdx.x;
  const int t = threadIdx.x;

  #pragma unroll
  for (int it = 0; it < 3; it++)
    ((float4*)scoresS)[it*256 + t] = ((const float4*)(Sg + (size_t)i*NH*LLEN))[it*256 + t];
  __syncthreads();

  const int h = t >> 5;
  const int g32 = t & 31;
  float sv[12];
  float mx = -3.0e38f;
  #pragma unroll
  for (int it = 0; it < 12; it++){
    float s = scoresS[h*LLEN + it*32 + g32];
    sv[it] = s;
    mx = fmaxf(mx, s);
  }
  #pragma unroll
  for (int mk = 1; mk < 32; mk <<= 1) mx = fmaxf(mx, __shfl_xor(mx, mk, 64));
  float den = 0.f;
  #pragma unroll
  for (int it = 0; it < 12; it++){ float e = __expf(sv[it] - mx); sv[it] = e; den += e; }
  #pragma unroll
  for (int mk = 1; mk < 32; mk <<= 1) den += __shfl_xor(den, mk, 64);
  float rden = 1.f / den;
  #pragma unroll
  for (int it = 0; it < 12; it++) scoresS[h*LLEN + it*32 + g32] = sv[it]*rden;
  __syncthreads();

  float a[8];
  #pragma unroll
  for (int k = 0; k < 8; k++) a[k] = 0.f;
  {
    const float* vp = Vm + t;
    const float* sp = scoresS + h*LLEN;
    #pragma unroll 2
    for (int j = 0; j < LLEN; j += 8){
      #pragma unroll
      for (int k = 0; k < 8; k++)
        a[k] = fmaf(sp[j+k], vp[(size_t)(j+k)*CDIM], a[k]);
    }
  }
  float x1 = ((a[0]+a[1]) + (a[2]+a[3])) + ((a[4]+a[5]) + (a[6]+a[7]));
  float x2v = 0.f;
  #pragma unroll
  for (int jt = 0; jt < 6; jt++)
    x2v += x2part[((size_t)jt*LLEN + i)*CDIM + t];
  xoutS[t] = x1 + x2v;
  __syncthreads();

  float b0a = bo[t], b1a = 0.f, b2a = 0.f, b3a = 0.f;
  #pragma unroll 4
  for (int c = 0; c < CDIM; c += 4){
    b0a = fmaf(xoutS[c+0], Wo[(size_t)(c+0)*CDIM + t], b0a);
    b1a = fmaf(xoutS[c+1], Wo[(size_t)(c+1)*CDIM + t], b1a);
    b2a = fmaf(xoutS[c+2], Wo[(size_t)(c+2)*CDIM + t], b2a);
    b3a = fmaf(xoutS[c+3], Wo[(size_t)(c+3)*CDIM + t], b3a);
  }
  out[(size_t)i*CDIM + t] = (b0a + b1a) + (b2a + b3a);
}

// ---------------------------------------------------------------------------
extern "C" void kernel_launch(void* const* d_in, const int* in_sizes, int n_in,
                              void* d_out, int out_size, void* d_ws, size_t ws_size,
                              hipStream_t stream)
{
  const float* x2d  = (const float*)d_in[0];
  const float* x3d  = (const float*)d_in[1];
  const float* Wq   = (const float*)d_in[2];
  const float* bq   = (const float*)d_in[3];
  const float* Wk   = (const float*)d_in[4];
  const float* bk   = (const float*)d_in[5];
  const float* Wv   = (const float*)d_in[6];
  const float* bv   = (const float*)d_in[7];
  const float* Wpre = (const float*)d_in[8];
  const float* bpre = (const float*)d_in[9];
  const float* ln_g = (const float*)d_in[10];
  const float* ln_b = (const float*)d_in[11];
  const float* Weq  = (const float*)d_in[12];
  const float* beq  = (const float*)d_in[13];
  const float* Wek  = (const float*)d_in[14];
  const float* bek  = (const float*)d_in[15];
  const float* Wo   = (const float*)d_in[16];
  const float* bo   = (const float*)d_in[17];
  float* out = (float*)d_out;

  float* Vm  = (float*)d_ws;                                 // 384*256 f32
  float* QmT = Vm + LLEN*CDIM;                               // 256*384 f32
  unsigned short* QmH = (unsigned short*)(QmT + CDIM*LLEN);  // 384*256 bf16
  unsigned short* PKt = QmH + LLEN*CDIM;                     // 8*24*64*8 bf16
  unsigned short* Pp  = PKt + LLEN*CDIM;                     // 128*256
  unsigned short* Pq  = Pp  + DIN*CDIM;                      // 256*256
  unsigned short* Pk  = Pq  + CDIM*CDIM;
  unsigned short* PWq = Pk  + CDIM*CDIM;
  unsigned short* PWk = PWq + CDIM*CDIM;
  unsigned short* PWv = PWk + CDIM*CDIM;
  float* Sg     = (float*)(PWv + CDIM*CDIM);                 // 384*8*384 f32
  float* x2part = Sg + (size_t)LLEN*NH*LLEN;                 // 6*384*256 f32

  pack_w<<<dim3(176), dim3(256), 0, stream>>>(Wpre, Weq, Wek, Wq, Wk, Wv,
                                              Pp, Pq, Pk, PWq, PWk, PWv);
  qkv_mfma<<<dim3(72), dim3(256), 0, stream>>>(x3d, bq, bk, bv, PWq, PWk, PWv,
                                               Vm, QmH, QmT, PKt);
  x3d_tiles<<<dim3(LLEN*6), dim3(256), 0, stream>>>(x2d, bpre, ln_g, ln_b, beq, bek,
                                                    QmT, QmH, PKt, Pp, Pq, Pk, Sg, x2part);
  finish<<<dim3(LLEN), dim3(256), 0, stream>>>(Sg, x2part, Vm, Wo, bo, out);
}

// Round 9
// 225.033 us; speedup vs baseline: 2.3746x; 1.0189x over previous
//
#include <hip/hip_runtime.h>
#include <hip/hip_bf16.h>

#define LLEN 384
#define CDIM 256
#define NH 8
#define HD 32
#define DIN 128
#define LN_EPS 1e-5f
#define SCL 0.17677669529663687f   // 1/sqrt(32)

typedef __attribute__((ext_vector_type(8))) short bh8;
typedef __attribute__((ext_vector_type(4))) float f32x4;
typedef __attribute__((ext_vector_type(4))) unsigned int u32x4;

__device__ __forceinline__ unsigned short f2bf(float f){
  unsigned int u = __float_as_uint(f);
  u += 0x7fffu + ((u >> 16) & 1u);
  return (unsigned short)(u >> 16);
}

// Pack two fp32 -> dword of 2 bf16 (RNE). HW v_cvt_pk_bf16_f32 on gfx950.
__device__ __forceinline__ unsigned int pkbf(float a, float b){
#if defined(__gfx950__) && __has_builtin(__builtin_amdgcn_cvt_pk_bf16_f32)
  typedef __attribute__((ext_vector_type(2))) __bf16 vbf2;
  vbf2 v = __builtin_amdgcn_cvt_pk_bf16_f32(a, b);
  union { vbf2 v; unsigned int u; } cv; cv.v = v; return cv.u;
#else
  return (unsigned int)f2bf(a) | ((unsigned int)f2bf(b) << 16);
#endif
}

// Packed tree-reduce: sum v[0..7] over the 16 lanes of a quad (lane bits 0-3).
// Returns: lane lm holds full sum of v[lm&7].
__device__ __forceinline__ float pk_reduce8(const float* v, int lane){
  bool b0 = lane & 1, b1 = lane & 2, b2 = lane & 4;
  float r0 = (b0 ? v[1] : v[0]) + __shfl_xor(b0 ? v[0] : v[1], 1, 64);
  float r1 = (b0 ? v[3] : v[2]) + __shfl_xor(b0 ? v[2] : v[3], 1, 64);
  float r2 = (b0 ? v[5] : v[4]) + __shfl_xor(b0 ? v[4] : v[5], 1, 64);
  float r3 = (b0 ? v[7] : v[6]) + __shfl_xor(b0 ? v[6] : v[7], 1, 64);
  float s0 = (b1 ? r1 : r0) + __shfl_xor(b1 ? r0 : r1, 2, 64);
  float s1 = (b1 ? r3 : r2) + __shfl_xor(b1 ? r2 : r3, 2, 64);
  float t0 = (b2 ? s1 : s0) + __shfl_xor(b2 ? s0 : s1, 4, 64);
  return t0 + __shfl_xor(t0, 8, 64);
}

// ---------------------------------------------------------------------------
// Pack weights (fp32 row-major [K][N]) into bf16 MFMA B-fragment order.
// ---------------------------------------------------------------------------
__global__ __launch_bounds__(256) void pack_w(
    const float* __restrict__ Wpre, const float* __restrict__ Weq,
    const float* __restrict__ Wek,  const float* __restrict__ Wq,
    const float* __restrict__ Wk,   const float* __restrict__ Wv,
    unsigned short* __restrict__ Pp, unsigned short* __restrict__ Pq,
    unsigned short* __restrict__ Pk, unsigned short* __restrict__ PWq,
    unsigned short* __restrict__ PWk, unsigned short* __restrict__ PWv)
{
  int tid = blockIdx.x * 256 + threadIdx.x;   // 176 blocks * 256 = 45056
  const float* W; unsigned short* P; int base;
  if      (tid <  4096){ W = Wpre; P = Pp;  base = tid;         }
  else if (tid < 12288){ W = Weq;  P = Pq;  base = tid -  4096; }
  else if (tid < 20480){ W = Wek;  P = Pk;  base = tid - 12288; }
  else if (tid < 28672){ W = Wq;   P = PWq; base = tid - 20480; }
  else if (tid < 36864){ W = Wk;   P = PWk; base = tid - 28672; }
  else                 { W = Wv;   P = PWv; base = tid - 36864; }
  int l   = base & 63;
  int c   = (base >> 6) & 15;
  int kc  = base >> 10;
  int krow = kc*32 + (l >> 4)*8;
  int col  = c*16 + (l & 15);
  unsigned int wds[4];
  #pragma unroll
  for (int p = 0; p < 4; p++){
    unsigned short lo = f2bf(W[(size_t)(krow + 2*p    )*CDIM + col]);
    unsigned short hi = f2bf(W[(size_t)(krow + 2*p + 1)*CDIM + col]);
    wds[p] = (unsigned int)lo | ((unsigned int)hi << 16);
  }
  uint4 v; v.x = wds[0]; v.y = wds[1]; v.z = wds[2]; v.w = wds[3];
  *(uint4*)(P + (size_t)base*8) = v;
}

// ---------------------------------------------------------------------------
// qkv: 72 blocks = jb(6) x m(3) x nq(4). Each wave owns one 16-col chunk.
// ---------------------------------------------------------------------------
__global__ __launch_bounds__(256) void qkv_mfma(
    const float* __restrict__ x3d,
    const float* __restrict__ bq, const float* __restrict__ bk, const float* __restrict__ bv,
    const unsigned short* __restrict__ PWq, const unsigned short* __restrict__ PWk,
    const unsigned short* __restrict__ PWv,
    float* __restrict__ Vm, unsigned short* __restrict__ QmH,
    float* __restrict__ QmT, unsigned short* __restrict__ PKt)
{
  __shared__ __align__(16) unsigned short Xb[64*264];
  const int bx = blockIdx.x;
  const int jb = bx / 12, rem = bx % 12;
  const int m = rem >> 2, nq = rem & 3;
  const int t  = threadIdx.x;
  const int w  = t >> 6, l = t & 63, q4 = l >> 4, lm = l & 15;

  const float* src = x3d + (size_t)jb*64*CDIM;
  #pragma unroll
  for (int it = 0; it < 16; it++){
    int idx = it*256 + t;
    int r = idx >> 6, k4 = (idx & 63) << 2;
    float4 v = *(const float4*)(src + (size_t)r*CDIM + k4);
    ushort4 b;
    b.x = f2bf(v.x); b.y = f2bf(v.y); b.z = f2bf(v.z); b.w = f2bf(v.w);
    *(ushort4*)(&Xb[r*264 + k4]) = b;
  }
  __syncthreads();

  const unsigned short* P = (m == 0) ? PWq : (m == 1) ? PWk : PWv;
  const float* bias       = (m == 0) ? bq  : (m == 1) ? bk  : bv;
  const int cidx = nq*4 + w;          // 16-col chunk this wave owns
  f32x4 acc[4];
  #pragma unroll
  for (int a = 0; a < 4; a++){ f32x4 z = {0.f,0.f,0.f,0.f}; acc[a] = z; }
  #pragma unroll
  for (int kc = 0; kc < 8; kc++){
    bh8 bf = *(const bh8*)(P + ((size_t)(kc*16 + cidx)*64 + l)*8);
    #pragma unroll
    for (int rt = 0; rt < 4; rt++){
      bh8 af = *(const bh8*)(&Xb[(rt*16 + lm)*264 + kc*32 + q4*8]);
      acc[rt] = __builtin_amdgcn_mfma_f32_16x16x32_bf16(af, bf, acc[rt], 0, 0, 0);
    }
  }
  {
    int c = cidx*16 + lm;
    float bb = bias[c];
    #pragma unroll
    for (int rt = 0; rt < 4; rt++)
      #pragma unroll
      for (int rg = 0; rg < 4; rg++){
        int row = jb*64 + rt*16 + q4*4 + rg;
        float v = acc[rt][rg] + bb;
        if (m == 0){
          QmH[(size_t)row*CDIM + c] = f2bf(v);
          QmT[(size_t)c*LLEN + row] = v;
        } else if (m == 1){
          int kc2 = c >> 5;            // head
          int jj2 = c & 7;
          int l2  = ((c >> 3) & 3)*16 + (row & 15);
          PKt[(((size_t)kc2*24 + (row >> 4))*64 + l2)*8 + jj2] = f2bf(v);
        } else {
          Vm[(size_t)row*CDIM + c] = v;
        }
      }
  }
}

// ---------------------------------------------------------------------------
// Main tile kernel: one block per (i, j-tile). 2304 blocks. R8 structure with
// async x2d staging: global_load_lds (fp32, XOR-swizzled 16B blocks realized
// on the GLOBAL side so the wave-uniform LDS constraint holds). GEMM1 reads
// fp32 from LDS + cvt_pk_bf16. qk1 loads issued BEFORE staging so their vmcnt
// wait does not drain the (younger, slower) staging loads.
// ---------------------------------------------------------------------------
__global__ __launch_bounds__(256, 3) void x3d_tiles(
  const float* __restrict__ x2d,
  const float* __restrict__ bpre, const float* __restrict__ ln_g, const float* __restrict__ ln_b,
  const float* __restrict__ beq,  const float* __restrict__ bek,
  const float* __restrict__ QmT,  const unsigned short* __restrict__ QmH,
  const unsigned short* __restrict__ PKt,
  const unsigned short* __restrict__ Pp, const unsigned short* __restrict__ Pq,
  const unsigned short* __restrict__ Pk,
  float* __restrict__ Sg, float* __restrict__ x2part)
{
  // EX holds X as fp32 (64x128, swizzled 16B blocks, 32768 B) during GEMM1,
  // then E as bf16 (64x264 shorts, 33792 B) for GEMM2/3.
  __shared__ __align__(16) unsigned short EX[64*264];      // 33792 B
  __shared__ float rowstat[4][64][2];                      //  2048 B
  __shared__ float muS[64], istdS[64];                     //   512 B
  __shared__ float bpreS[CDIM], gS[CDIM], bSh[CDIM], beqS[CDIM], bekS[CDIM]; // 5120 B
  __shared__ float qk1S[NH*64];                            //  2048 B

  const int bx = blockIdx.x;
  const int i = bx / 6, jt = bx % 6, j0 = jt * 64;
  const int t = threadIdx.x;
  const int w = t >> 6, l = t & 63, q4 = l >> 4, lm = l & 15;
  const int wbase = w << 6;

  // ---- qk1 fragment loads FIRST (oldest in vmcnt queue) ----
  bh8 aqv[2], kf[2][4];
  #pragma unroll
  for (int hh = 0; hh < 2; hh++){
    int h = 2*w + hh;
    aqv[hh] = *(const bh8*)(QmH + (size_t)i*CDIM + h*HD + q4*8);
    #pragma unroll
    for (int ct = 0; ct < 4; ct++)
      kf[hh][ct] = *(const bh8*)(PKt + (((size_t)h*24 + (jt*4 + ct))*64 + l)*8);
  }

  // ---- async stage x2d tile (64x128 fp32, 32 KB) direct to LDS ----
  // LDS block P (16B) = w*512 + it*64 + l; row = P>>5, pb = P&31;
  // global source block = pb ^ (row&7)  (XOR swizzle on the global side).
  {
    const char* gtile = (const char*)(x2d + ((size_t)i*LLEN + j0)*DIN);
    #pragma unroll
    for (int it = 0; it < 8; it++){
      int P   = w*512 + it*64 + l;
      int row = P >> 5;
      int blk = (P & 31) ^ (row & 7);
      const void* gp = gtile + ((size_t)row*512 + ((size_t)blk << 4));
      unsigned short* lp = EX + (w*4096 + it*512);
      __builtin_amdgcn_global_load_lds(
          (const __attribute__((address_space(1))) void*)gp,
          (__attribute__((address_space(3))) void*)lp, 16, 0, 0);
    }
  }

  // ---- qk1 MFMAs (wait only on their own loads; staging stays in flight) ----
  #pragma unroll
  for (int hh = 0; hh < 2; hh++){
    int h = 2*w + hh;
    #pragma unroll
    for (int ct = 0; ct < 4; ct++){
      f32x4 z = {0.f,0.f,0.f,0.f};
      f32x4 a1 = __builtin_amdgcn_mfma_f32_16x16x32_bf16(aqv[hh], kf[hh][ct], z, 0, 0, 0);
      if (q4 == 0) qk1S[h*64 + ct*16 + lm] = a1[0];
    }
  }

  bpreS[t] = bpre[t]; gS[t] = ln_g[t]; bSh[t] = ln_b[t];
  beqS[t]  = beq[t];  bekS[t] = bek[t];
  __syncthreads();   // drains staging too

  // ---- GEMM1: Epre = X @ Wpre (fp32 LDS reads + cvt) ----
  const float* XF = (const float*)EX;
  f32x4 acc[4][4];
  #pragma unroll
  for (int a = 0; a < 4; a++)
    #pragma unroll
    for (int b = 0; b < 4; b++){ f32x4 z = {0.f,0.f,0.f,0.f}; acc[a][b] = z; }
  #pragma unroll
  for (int kc = 0; kc < 4; kc++){
    bh8 af[4];
    #pragma unroll
    for (int rt = 0; rt < 4; rt++){
      int row = rt*16 + lm;
      int sw  = row & 7;
      int blk0 = kc*8 + q4*2;
      f32x4 a0 = *(const f32x4*)(XF + row*128 + ((blk0       ^ sw) << 2));
      f32x4 a1 = *(const f32x4*)(XF + row*128 + (((blk0 + 1) ^ sw) << 2));
      union { unsigned int u[4]; bh8 v; } cv;
      cv.u[0] = pkbf(a0[0], a0[1]); cv.u[1] = pkbf(a0[2], a0[3]);
      cv.u[2] = pkbf(a1[0], a1[1]); cv.u[3] = pkbf(a1[2], a1[3]);
      af[rt] = cv.v;
    }
    #pragma unroll
    for (int ct = 0; ct < 4; ct++){
      bh8 bf = *(const bh8*)(Pp + ((size_t)(kc*16 + (w*4 + ct))*64 + l)*8);
      #pragma unroll
      for (int rt = 0; rt < 4; rt++)
        acc[rt][ct] = __builtin_amdgcn_mfma_f32_16x16x32_bf16(af[rt], bf, acc[rt][ct], 0, 0, 0);
    }
  }

  // ---- + bpre, per-row LN stats via packed tree-reduce ----
  #pragma unroll
  for (int rt = 0; rt < 4; rt++){
    float v[8];   // v[2rg+0]=sum partial, v[2rg+1]=sq partial
    #pragma unroll
    for (int p = 0; p < 8; p++) v[p] = 0.f;
    #pragma unroll
    for (int ct = 0; ct < 4; ct++){
      float bb = bpreS[wbase + ct*16 + lm];
      #pragma unroll
      for (int rg = 0; rg < 4; rg++){
        float x = acc[rt][ct][rg] + bb;
        acc[rt][ct][rg] = x;
        v[2*rg]   += x;
        v[2*rg+1] += x*x;
      }
    }
    float red = pk_reduce8(v, lm);
    if (lm < 8){
      int p = lm;                       // p = 2rg+which
      rowstat[w][rt*16 + q4*4 + (p >> 1)][p & 1] = red;
    }
  }
  __syncthreads();
  if (t < 64){
    float s  = rowstat[0][t][0] + rowstat[1][t][0] + rowstat[2][t][0] + rowstat[3][t][0];
    float s2 = rowstat[0][t][1] + rowstat[1][t][1] + rowstat[2][t][1] + rowstat[3][t][1];
    float mu = s * (1.f/256.f);
    float var = s2 * (1.f/256.f) - mu*mu;
    muS[t] = mu;
    istdS[t] = rsqrtf(var + LN_EPS);
  }
  __syncthreads();

  // ---- LN + ReLU -> bf16 E tile (stride 264, overwrites X) ----
  #pragma unroll
  for (int rt = 0; rt < 4; rt++){
    #pragma unroll
    for (int rg = 0; rg < 4; rg++){
      int row = rt*16 + q4*4 + rg;
      float mu = muS[row], is = istdS[row];
      #pragma unroll
      for (int ct = 0; ct < 4; ct++){
        int c = wbase + ct*16 + lm;
        float v = (acc[rt][ct][rg] - mu)*is*gS[c] + bSh[c];
        v = fmaxf(v, 0.f);
        EX[row*264 + c] = f2bf(v);
      }
    }
  }
  __syncthreads();

  // ---- GEMM2: EFK = E @ Wek ----
  #pragma unroll
  for (int a = 0; a < 4; a++)
    #pragma unroll
    for (int b = 0; b < 4; b++){ f32x4 z = {0.f,0.f,0.f,0.f}; acc[a][b] = z; }
  #pragma unroll
  for (int kc = 0; kc < 8; kc++){
    bh8 af[4];
    #pragma unroll
    for (int rt = 0; rt < 4; rt++)
      af[rt] = *(const bh8*)(&EX[(rt*16 + lm)*264 + kc*32 + q4*8]);
    #pragma unroll
    for (int ct = 0; ct < 4; ct++){
      bh8 bf = *(const bh8*)(Pk + ((size_t)(kc*16 + (w*4 + ct))*64 + l)*8);
      #pragma unroll
      for (int rt = 0; rt < 4; rt++)
        acc[rt][ct] = __builtin_amdgcn_mfma_f32_16x16x32_bf16(af[rt], bf, acc[rt][ct], 0, 0, 0);
    }
  }

  // ---- scores: term2 packed-reduce + qk1 + scale; keep in screg ----
  float screg[4];
  #pragma unroll
  for (int rt = 0; rt < 4; rt++){
    float v[8];   // v[2rg+which]
    #pragma unroll
    for (int p = 0; p < 8; p++) v[p] = 0.f;
    #pragma unroll
    for (int ct = 0; ct < 4; ct++){
      int c = wbase + ct*16 + lm;
      float bek_ = bekS[c];
      float4 qv = *(const float4*)(QmT + (size_t)c*LLEN + j0 + rt*16 + q4*4);
      int wh = ct >> 1;
      v[0 + wh] += (acc[rt][ct][0] + bek_) * qv.x;
      v[2 + wh] += (acc[rt][ct][1] + bek_) * qv.y;
      v[4 + wh] += (acc[rt][ct][2] + bek_) * qv.z;
      v[6 + wh] += (acc[rt][ct][3] + bek_) * qv.w;
    }
    float red = pk_reduce8(v, lm);
    int p = lm & 7;                     // p = 2rg + which
    int jloc = rt*16 + q4*4 + (p >> 1);
    float sc = (red + qk1S[(2*w + (p & 1))*64 + jloc]) * SCL;
    screg[rt] = sc;
    if (lm < 8)
      Sg[((size_t)i*NH + 2*w + (p & 1))*LLEN + j0 + jloc] = sc;
  }

  // ---- GEMM3: EFQ = E @ Weq ----
  #pragma unroll
  for (int a = 0; a < 4; a++)
    #pragma unroll
    for (int b = 0; b < 4; b++){ f32x4 z = {0.f,0.f,0.f,0.f}; acc[a][b] = z; }
  #pragma unroll
  for (int kc = 0; kc < 8; kc++){
    bh8 af[4];
    #pragma unroll
    for (int rt = 0; rt < 4; rt++)
      af[rt] = *(const bh8*)(&EX[(rt*16 + lm)*264 + kc*32 + q4*8]);
    #pragma unroll
    for (int ct = 0; ct < 4; ct++){
      bh8 bf = *(const bh8*)(Pq + ((size_t)(kc*16 + (w*4 + ct))*64 + l)*8);
      #pragma unroll
      for (int rt = 0; rt < 4; rt++)
        acc[rt][ct] = __builtin_amdgcn_mfma_f32_16x16x32_bf16(af[rt], bf, acc[rt][ct], 0, 0, 0);
    }
  }

  // ---- x2 partial: x2[h,c] += scores[h,j]*efq[j,c] (pre-softmax scaled) ----
  float x2p[4] = {0.f, 0.f, 0.f, 0.f};
  float bq4[4];
  #pragma unroll
  for (int ct = 0; ct < 4; ct++) bq4[ct] = beqS[wbase + ct*16 + lm];
  #pragma unroll
  for (int rt = 0; rt < 4; rt++){
    float sb[8];
    #pragma unroll
    for (int p = 0; p < 8; p++)
      sb[p] = __shfl(screg[rt], (l & 48) | p, 64);
    #pragma unroll
    for (int ct = 0; ct < 4; ct++){
      int wh = ct >> 1;
      #pragma unroll
      for (int rg = 0; rg < 4; rg++)
        x2p[ct] = fmaf(sb[2*rg + wh], acc[rt][ct][rg] + bq4[ct], x2p[ct]);
    }
  }
  {
    bool b4 = l & 16, b5 = l & 32;
    float r0 = (b4 ? x2p[1] : x2p[0]) + __shfl_xor(b4 ? x2p[0] : x2p[1], 16, 64);
    float r1 = (b4 ? x2p[3] : x2p[2]) + __shfl_xor(b4 ? x2p[2] : x2p[3], 16, 64);
    float q  = (b5 ? r1 : r0) + __shfl_xor(b5 ? r0 : r1, 32, 64);
    int ctq = ((l >> 4) & 1) | (((l >> 5) & 1) << 1);
    x2part[((size_t)jt*LLEN + i)*CDIM + wbase + ctq*16 + lm] = q;
  }
}

// ---------------------------------------------------------------------------
// finish: softmax + x1 + x2 + out-proj. 384 blocks. x1 with 8-deep ILP.
// ---------------------------------------------------------------------------
__global__ __launch_bounds__(256) void finish(
    const float* __restrict__ Sg, const float* __restrict__ x2part,
    const float* __restrict__ Vm, const float* __restrict__ Wo,
    const float* __restrict__ bo, float* __restrict__ out)
{
  __shared__ float scoresS[NH*LLEN];   // 12 KB
  __shared__ float xoutS[CDIM];
  const int i = blockIdx.x;
  const int t = threadIdx.x;

  #pragma unroll
  for (int it = 0; it < 3; it++)
    ((float4*)scoresS)[it*256 + t] = ((const float4*)(Sg + (size_t)i*NH*LLEN))[it*256 + t];
  __syncthreads();

  const int h = t >> 5;
  const int g32 = t & 31;
  float sv[12];
  float mx = -3.0e38f;
  #pragma unroll
  for (int it = 0; it < 12; it++){
    float s = scoresS[h*LLEN + it*32 + g32];
    sv[it] = s;
    mx = fmaxf(mx, s);
  }
  #pragma unroll
  for (int mk = 1; mk < 32; mk <<= 1) mx = fmaxf(mx, __shfl_xor(mx, mk, 64));
  float den = 0.f;
  #pragma unroll
  for (int it = 0; it < 12; it++){ float e = __expf(sv[it] - mx); sv[it] = e; den += e; }
  #pragma unroll
  for (int mk = 1; mk < 32; mk <<= 1) den += __shfl_xor(den, mk, 64);
  float rden = 1.f / den;
  #pragma unroll
  for (int it = 0; it < 12; it++) scoresS[h*LLEN + it*32 + g32] = sv[it]*rden;
  __syncthreads();

  float a[8];
  #pragma unroll
  for (int k = 0; k < 8; k++) a[k] = 0.f;
  {
    const float* vp = Vm + t;
    const float* sp = scoresS + h*LLEN;
    #pragma unroll 2
    for (int j = 0; j < LLEN; j += 8){
      #pragma unroll
      for (int k = 0; k < 8; k++)
        a[k] = fmaf(sp[j+k], vp[(size_t)(j+k)*CDIM], a[k]);
    }
  }
  float x1 = ((a[0]+a[1]) + (a[2]+a[3])) + ((a[4]+a[5]) + (a[6]+a[7]));
  float x2v = 0.f;
  #pragma unroll
  for (int jt = 0; jt < 6; jt++)
    x2v += x2part[((size_t)jt*LLEN + i)*CDIM + t];
  xoutS[t] = x1 + x2v;
  __syncthreads();

  float b0a = bo[t], b1a = 0.f, b2a = 0.f, b3a = 0.f;
  #pragma unroll 4
  for (int c = 0; c < CDIM; c += 4){
    b0a = fmaf(xoutS[c+0], Wo[(size_t)(c+0)*CDIM + t], b0a);
    b1a = fmaf(xoutS[c+1], Wo[(size_t)(c+1)*CDIM + t], b1a);
    b2a = fmaf(xoutS[c+2], Wo[(size_t)(c+2)*CDIM + t], b2a);
    b3a = fmaf(xoutS[c+3], Wo[(size_t)(c+3)*CDIM + t], b3a);
  }
  out[(size_t)i*CDIM + t] = (b0a + b1a) + (b2a + b3a);
}

// ---------------------------------------------------------------------------
extern "C" void kernel_launch(void* const* d_in, const int* in_sizes, int n_in,
                              void* d_out, int out_size, void* d_ws, size_t ws_size,
                              hipStream_t stream)
{
  const float* x2d  = (const float*)d_in[0];
  const float* x3d  = (const float*)d_in[1];
  const float* Wq   = (const float*)d_in[2];
  const float* bq   = (const float*)d_in[3];
  const float* Wk   = (const float*)d_in[4];
  const float* bk   = (const float*)d_in[5];
  const float* Wv   = (const float*)d_in[6];
  const float* bv   = (const float*)d_in[7];
  const float* Wpre = (const float*)d_in[8];
  const float* bpre = (const float*)d_in[9];
  const float* ln_g = (const float*)d_in[10];
  const float* ln_b = (const float*)d_in[11];
  const float* Weq  = (const float*)d_in[12];
  const float* beq  = (const float*)d_in[13];
  const float* Wek  = (const float*)d_in[14];
  const float* bek  = (const float*)d_in[15];
  const float* Wo   = (const float*)d_in[16];
  const float* bo   = (const float*)d_in[17];
  float* out = (float*)d_out;

  float* Vm  = (float*)d_ws;                                 // 384*256 f32
  float* QmT = Vm + LLEN*CDIM;                               // 256*384 f32
  unsigned short* QmH = (unsigned short*)(QmT + CDIM*LLEN);  // 384*256 bf16
  unsigned short* PKt = QmH + LLEN*CDIM;                     // 8*24*64*8 bf16
  unsigned short* Pp  = PKt + LLEN*CDIM;                     // 128*256
  unsigned short* Pq  = Pp  + DIN*CDIM;                      // 256*256
  unsigned short* Pk  = Pq  + CDIM*CDIM;
  unsigned short* PWq = Pk  + CDIM*CDIM;
  unsigned short* PWk = PWq + CDIM*CDIM;
  unsigned short* PWv = PWk + CDIM*CDIM;
  float* Sg     = (float*)(PWv + CDIM*CDIM);                 // 384*8*384 f32
  float* x2part = Sg + (size_t)LLEN*NH*LLEN;                 // 6*384*256 f32

  pack_w<<<dim3(176), dim3(256), 0, stream>>>(Wpre, Weq, Wek, Wq, Wk, Wv,
                                              Pp, Pq, Pk, PWq, PWk, PWv);
  qkv_mfma<<<dim3(72), dim3(256), 0, stream>>>(x3d, bq, bk, bv, PWq, PWk, PWv,
                                               Vm, QmH, QmT, PKt);
  x3d_tiles<<<dim3(LLEN*6), dim3(256), 0, stream>>>(x2d, bpre, ln_g, ln_b, beq, bek,
                                                    QmT, QmH, PKt, Pp, Pq, Pk, Sg, x2part);
  finish<<<dim3(LLEN), dim3(256), 0, stream>>>(Sg, x2part, Vm, Wo, bo, out);
}